// Round 12
// baseline (204.707 us; speedup 1.0000x reference)
//
#include <hip/hip_runtime.h>

#define NPIX 262144   // B*H*H = 4*256*256
#define M1C 4096
#define M2C 512
#define E1C 65536
#define E2C 8192

// ---- workspace layout (4-byte element offsets) ----
// zeroed region (int histograms only):
constexpr int IOFF_H1   = 0;                 // 4096
constexpr int IOFF_HC2  = IOFF_H1  + M1C;    // 512
constexpr int IOFF_HE1  = IOFF_HC2 + M2C;    // 4096
constexpr int IOFF_HE2  = IOFF_HE1 + M1C;    // 512
constexpr int ZEROI_END = IOFF_HE2 + M2C;    // 9216 ints

constexpr int IOFF_ST1   = ZEROI_END;              // 4097
constexpr int IOFF_CU1   = IOFF_ST1  + M1C + 1;    // 4096
constexpr int IOFF_STC2  = IOFF_CU1  + M1C;        // 513
constexpr int IOFF_CUC2  = IOFF_STC2 + M2C + 1;    // 512
constexpr int IOFF_STE1  = IOFF_CUC2 + M2C;        // 4097
constexpr int IOFF_CUE1  = IOFF_STE1 + M1C + 1;    // 4096
constexpr int IOFF_STE2  = IOFF_CUE1 + M1C;        // 513
constexpr int IOFF_CUE2  = IOFF_STE2 + M2C + 1;    // 512
constexpr int IOFF_PLIST = IOFF_CUE2 + M2C;        // 262144 (pixels sorted by cluster)
constexpr int IOFF_R2L   = IOFF_PLIST + NPIX;      // 4096
constexpr int IOFF_E1L   = IOFF_R2L + M1C;         // 65536
constexpr int IOFF_E2L   = IOFF_E1L + E1C;         // 8192
constexpr int IEND0      = IOFF_E2L + E2C;
constexpr int IEND       = (IEND0 + 3) & ~3;       // 16B-align float region

// float scratch:
constexpr int OFF_S1CR  = IEND;                    // 4096*4 raw coord sums
constexpr int OFF_C1    = OFF_S1CR + M1C*4;        // 4096 counts
constexpr int OFF_X1FC  = OFF_C1 + M1C;            // 4096*64 (t1 out, gc1 in)
constexpr int OFF_X1    = OFF_X1FC + M1C*64;       // 4096*64 (gc1 out, pool in)
constexpr int OFF_X2FC  = OFF_X1 + M1C*64;         // 512*64  (t2 out, gc2 in)
constexpr int OFF_JSF1  = OFF_X2FC + M2C*64;       // 4096*20 (80B rows, 16B-aligned)
constexpr int OFF_JSF2  = OFF_JSF1 + M1C*20;       // 512*20
constexpr int OFF_WT    = OFF_JSF2 + M2C*20;       // transposed weights (see table below)

// transposed-weight offsets (floats, relative to ws+OFF_WT); WT[c][k] = W[k][c]
constexpr int T_T1WI  = 0;       // 100x68
constexpr int T_T1WH0 = 6800;    // 100x100
constexpr int T_T1WH1 = 16800;   // 100x100
constexpr int T_T1WO  = 26800;   // 64x100
constexpr int T_T2WI  = 33200;
constexpr int T_T2WH0 = 40000;
constexpr int T_T2WH1 = 50000;
constexpr int T_T2WO  = 60000;
constexpr int T_QWI   = 66400;   // 100x64
constexpr int T_QWH0  = 72800;
constexpr int T_QWH1  = 82800;
constexpr int T_QWO   = 92800;   // 18x100
constexpr int T_G1WN  = 94600;   // 64x64
constexpr int T_G1WS  = 98696;
constexpr int T_G2WN  = 102792;
constexpr int T_G2WS  = 106888;
constexpr int WT_END  = 110984;

// ---------------- prep: zero histograms + transpose all weights ----------------
__device__ __forceinline__ void tr1(const float* __restrict__ W, float* __restrict__ WT,
                                    int K, int N, int idx) {
  int c = idx / K, k = idx - c*K;
  WT[idx] = W[k*N + c];
}

__global__ __launch_bounds__(256) void prep(
    const float* t1_wi, const float* t1_wh, const float* t1_wo,
    const float* t2_wi, const float* t2_wh, const float* t2_wo,
    const float* q_wi,  const float* q_wh,  const float* q_wo,
    const float* g1wn, const float* g1ws, const float* g2wn, const float* g2ws,
    int* __restrict__ wsI, float* __restrict__ wt) {
  int i = blockIdx.x*256 + threadIdx.x;
  if (i < ZEROI_END) { wsI[i] = 0; return; }
  int idx = i - ZEROI_END;
  if (idx >= WT_END) return;
  if      (idx < T_T1WH0) tr1(t1_wi,        wt+T_T1WI,  68, 100, idx-T_T1WI);
  else if (idx < T_T1WH1) tr1(t1_wh,        wt+T_T1WH0, 100,100, idx-T_T1WH0);
  else if (idx < T_T1WO)  tr1(t1_wh+10000,  wt+T_T1WH1, 100,100, idx-T_T1WH1);
  else if (idx < T_T2WI)  tr1(t1_wo,        wt+T_T1WO,  100, 64, idx-T_T1WO);
  else if (idx < T_T2WH0) tr1(t2_wi,        wt+T_T2WI,  68, 100, idx-T_T2WI);
  else if (idx < T_T2WH1) tr1(t2_wh,        wt+T_T2WH0, 100,100, idx-T_T2WH0);
  else if (idx < T_T2WO)  tr1(t2_wh+10000,  wt+T_T2WH1, 100,100, idx-T_T2WH1);
  else if (idx < T_QWI)   tr1(t2_wo,        wt+T_T2WO,  100, 64, idx-T_T2WO);
  else if (idx < T_QWH0)  tr1(q_wi,         wt+T_QWI,   64, 100, idx-T_QWI);
  else if (idx < T_QWH1)  tr1(q_wh,         wt+T_QWH0,  100,100, idx-T_QWH0);
  else if (idx < T_QWO)   tr1(q_wh+10000,   wt+T_QWH1,  100,100, idx-T_QWH1);
  else if (idx < T_G1WN)  tr1(q_wo,         wt+T_QWO,   100, 18, idx-T_QWO);
  else if (idx < T_G1WS)  tr1(g1wn,         wt+T_G1WN,  64,  64, idx-T_G1WN);
  else if (idx < T_G2WN)  tr1(g1ws,         wt+T_G1WS,  64,  64, idx-T_G1WS);
  else if (idx < T_G2WS)  tr1(g2wn,         wt+T_G2WN,  64,  64, idx-T_G2WN);
  else                    tr1(g2ws,         wt+T_G2WS,  64,  64, idx-T_G2WS);
}

// ---------------- fused histograms ----------------
__global__ __launch_bounds__(256) void build_hist(
    const int* __restrict__ c1, const int* __restrict__ c2,
    const int* __restrict__ e1, const int* __restrict__ e2, int* __restrict__ wsI) {
  int i = blockIdx.x*256 + threadIdx.x;
  if (i < NPIX) {
    atomicAdd(&wsI[IOFF_H1 + c1[i]], 1);
  } else if (i < NPIX + M1C) {
    atomicAdd(&wsI[IOFF_HC2 + c2[i - NPIX]], 1);
  } else if (i < NPIX + M1C + E1C) {
    int e = i - NPIX - M1C;
    atomicAdd(&wsI[IOFF_HE1 + e1[E1C + e]], 1);
  } else {
    int e = i - NPIX - M1C - E1C;
    atomicAdd(&wsI[IOFF_HE2 + e2[E2C + e]], 1);
  }
}

// ---------------- exclusive scan, one block per histogram ----------------
__global__ __launch_bounds__(1024) void scan_kernel(int* __restrict__ wsI) {
  const int* hist; int* start; int* curs; int n;
  if (blockIdx.x == 0)      { hist = wsI+IOFF_H1;  start = wsI+IOFF_ST1;  curs = wsI+IOFF_CU1;  n = M1C; }
  else if (blockIdx.x == 1) { hist = wsI+IOFF_HC2; start = wsI+IOFF_STC2; curs = wsI+IOFF_CUC2; n = M2C; }
  else if (blockIdx.x == 2) { hist = wsI+IOFF_HE1; start = wsI+IOFF_STE1; curs = wsI+IOFF_CUE1; n = M1C; }
  else                      { hist = wsI+IOFF_HE2; start = wsI+IOFF_STE2; curs = wsI+IOFF_CUE2; n = M2C; }
  __shared__ int part[1024];
  int t = threadIdx.x, base = t*4, sum = 0;
  int loc0, loc1, loc2, loc3;
  loc0 = sum; sum += (base+0 < n) ? hist[base+0] : 0;
  loc1 = sum; sum += (base+1 < n) ? hist[base+1] : 0;
  loc2 = sum; sum += (base+2 < n) ? hist[base+2] : 0;
  loc3 = sum; sum += (base+3 < n) ? hist[base+3] : 0;
  part[t] = sum;
  __syncthreads();
  for (int off = 1; off < 1024; off <<= 1) {
    int v = (t >= off) ? part[t-off] : 0;
    __syncthreads();
    part[t] += v;
    __syncthreads();
  }
  int excl = (t == 0) ? 0 : part[t-1];
  if (base+0 < n) { start[base+0] = excl+loc0; curs[base+0] = excl+loc0; }
  if (base+1 < n) { start[base+1] = excl+loc1; curs[base+1] = excl+loc1; }
  if (base+2 < n) { start[base+2] = excl+loc2; curs[base+2] = excl+loc2; }
  if (base+3 < n) { start[base+3] = excl+loc3; curs[base+3] = excl+loc3; }
  if (t == 0) start[n] = part[1023];
}

// ---------------- fused scatter into bins ----------------
__global__ __launch_bounds__(256) void scatter_all(
    const int* __restrict__ c1, const int* __restrict__ c2,
    const int* __restrict__ e1, const int* __restrict__ e2, int* __restrict__ wsI) {
  int i = blockIdx.x*256 + threadIdx.x;
  if (i < NPIX) {
    int s = c1[i];
    int pos = atomicAdd(&wsI[IOFF_CU1 + s], 1);
    wsI[IOFF_PLIST + pos] = i;
  } else if (i < NPIX + M1C) {
    int r = i - NPIX;
    int pos = atomicAdd(&wsI[IOFF_CUC2 + c2[r]], 1);
    wsI[IOFF_R2L + pos] = r;
  } else if (i < NPIX + M1C + E1C) {
    int e = i - NPIX - M1C;
    int pos = atomicAdd(&wsI[IOFF_CUE1 + e1[E1C + e]], 1);
    wsI[IOFF_E1L + pos] = e1[e];
  } else {
    int e = i - NPIX - M1C - E1C;
    int pos = atomicAdd(&wsI[IOFF_CUE2 + e2[E2C + e]], 1);
    wsI[IOFF_E2L + pos] = e2[e];
  }
}

// ---------------- block dense layer with TRANSPOSED weights (float4 streams) ----------------
template<int NIN, int NOUT, int R, bool RELU>
__device__ __forceinline__ void block_layer_T(
    const float* __restrict__ WT,    // [NOUT][NIN]
    const float* __restrict__ B,
    const float* __restrict__ actIn, float* __restrict__ actOut, int tid) {
  constexpr int NG  = 256 / NOUT;
  constexpr int RPT = (R + NG - 1) / NG;
  static_assert(NIN % 4 == 0, "NIN must be multiple of 4");
  int c  = tid % NOUT;
  int rg = tid / NOUT;
  if (rg < NG) {
    float acc[RPT];
    #pragma unroll
    for (int i = 0; i < RPT; ++i) acc[i] = 0.f;
    const float4* wrow = reinterpret_cast<const float4*>(WT + c*NIN);
    #pragma unroll 4
    for (int kc = 0; kc < NIN/4; ++kc) {
      float4 w = wrow[kc];
      #pragma unroll
      for (int i = 0; i < RPT; ++i) {
        int r = rg + i*NG;
        if (r < R) {
          float4 a = *reinterpret_cast<const float4*>(actIn + r*NIN + kc*4);
          acc[i] = fmaf(a.x, w.x, fmaf(a.y, w.y, fmaf(a.z, w.z, fmaf(a.w, w.w, acc[i]))));
        }
      }
    }
    float b = B[c];
    #pragma unroll
    for (int i = 0; i < RPT; ++i) {
      int r = rg + i*NG;
      if (r < R) {
        float v = acc[i] + b;
        actOut[r*NOUT + c] = RELU ? fmaxf(v, 0.f) : v;
      }
    }
  }
  __syncthreads();
}

// ==================== K1: conv-linearity gather + t1 MLP (4 clusters/block) ====================
__global__ __launch_bounds__(256) void k1_gather_t1(
    const float* __restrict__ img, const float* __restrict__ cw, const float* __restrict__ cb,
    const int* __restrict__ start, const int* __restrict__ plist,
    const float* __restrict__ wt,
    const float* t1_bi, const float* t1_bh, const float* t1_bo,
    float* __restrict__ x1fc, float* __restrict__ s1c_raw, float* __restrict__ c1f,
    float* __restrict__ jsf1) {
  int tid = threadIdx.x, wv = tid >> 6, l = tid & 63;
  int s = blockIdx.x*4 + wv;
  __shared__ __align__(16) float bufA[4*100];
  __shared__ __align__(16) float bufB[4*100];
  // --- gather phase (wave per cluster) ---
  int p0 = start[s], p1 = start[s+1];
  int count = p1 - p0;
  float ps[27];
  #pragma unroll
  for (int k = 0; k < 27; ++k) ps[k] = 0.f;
  float sy = 0.f, sx = 0.f, syy = 0.f, sxx = 0.f;
  for (int p = p0 + l; p < p1; p += 64) {
    int n = plist[p];
    int b = n >> 16, pp = n & 65535, i = pp >> 8, j = pp & 255;
    #pragma unroll
    for (int di = 0; di < 3; ++di) {
      int y = i + di - 1;
      #pragma unroll
      for (int dj = 0; dj < 3; ++dj) {
        int x = j + dj - 1;
        int k = (di*3 + dj)*3;
        if ((unsigned)y < 256u && (unsigned)x < 256u) {
          int base = ((b << 16) + (y << 8) + x) * 3;
          ps[k+0] += img[base];
          ps[k+1] += img[base+1];
          ps[k+2] += img[base+2];
        }
      }
    }
    float yi = i * (1.0f/256.0f), xj = j * (1.0f/256.0f);
    sy += yi; sx += xj; syy += yi*yi; sxx += xj*xj;
  }
  #pragma unroll
  for (int m = 1; m < 64; m <<= 1) {
    #pragma unroll
    for (int k = 0; k < 27; ++k) ps[k] += __shfl_xor(ps[k], m);
    sy  += __shfl_xor(sy,  m);
    sx  += __shfl_xor(sx,  m);
    syy += __shfl_xor(syy, m);
    sxx += __shfl_xor(sxx, m);
  }
  float inv = 1.0f / fmaxf((float)count, 1.0f);
  float o = cb[l];
  #pragma unroll
  for (int k = 0; k < 27; ++k) o = fmaf(ps[k]*inv, cw[k*64 + l], o);
  bufA[wv*68 + l] = count ? o : 0.f;                // x1cat row lives in LDS only
  if (l == 0) {
    bufA[wv*68 + 64] = sy*inv;
    bufA[wv*68 + 65] = sx*inv;
    bufA[wv*68 + 66] = syy*inv;
    bufA[wv*68 + 67] = sxx*inv;
    s1c_raw[s*4+0] = sy; s1c_raw[s*4+1] = sx;
    s1c_raw[s*4+2] = syy; s1c_raw[s*4+3] = sxx;
    jsf1[s*20 + 18] = sy*inv;
    jsf1[s*20 + 19] = sx*inv;
    c1f[s] = (float)count;
  }
  __syncthreads();
  // --- t1 MLP on the block's 4 rows (transposed weights) ---
  block_layer_T<68,100,4,true>(wt+T_T1WI,  t1_bi,     bufA, bufB, tid);
  block_layer_T<100,100,4,true>(wt+T_T1WH0, t1_bh,     bufB, bufA, tid);
  block_layer_T<100,100,4,true>(wt+T_T1WH1, t1_bh+100, bufA, bufB, tid);
  block_layer_T<100,64,4,false>(wt+T_T1WO,  t1_bo,     bufB, bufA, tid);
  int r0 = blockIdx.x*4;
  for (int o2 = tid; o2 < 4*64; o2 += 256) x1fc[r0*64 + o2] = bufA[o2];
}

// ==================== K2: gc1 + q-MLP(x1) (4 rows/block, 1024 blocks) ====================
__global__ __launch_bounds__(256) void k2_gc1_q(
    const int* __restrict__ startE, const int* __restrict__ elist,
    const float* __restrict__ xin,
    const float* __restrict__ wt, const float* bias,
    const float* q_bi, const float* q_bh, const float* q_bo,
    float* __restrict__ x1_ws, float* __restrict__ out_f, float* __restrict__ jsf) {
  int tid = threadIdx.x, wv = tid >> 6, l = tid & 63;
  int d = blockIdx.x*4 + wv;
  __shared__ __align__(16) float bufA[4*100];
  __shared__ __align__(16) float bufB[4*100];
  __shared__ __align__(16) float smW[4*128];
  float* sm = smW + wv*128;
  // --- graph conv ---
  int p0 = startE[d], p1 = startE[d+1];
  float acc = 0.f;
  for (int p = p0; p < p1; ++p) acc += xin[elist[p]*64 + l];
  sm[l]      = acc / fmaxf((float)(p1 - p0), 1.0f);
  sm[64 + l] = xin[d*64 + l];
  __syncthreads();
  float o = bias[l];
  {
    const float4* w1 = reinterpret_cast<const float4*>(wt + T_G1WN + l*64);
    const float4* w2 = reinterpret_cast<const float4*>(wt + T_G1WS + l*64);
    const float4* sa = reinterpret_cast<const float4*>(sm);
    const float4* sb = reinterpret_cast<const float4*>(sm + 64);
    #pragma unroll
    for (int k4 = 0; k4 < 16; ++k4) {
      float4 wa = w1[k4], wb = w2[k4], aa = sa[k4], ab = sb[k4];
      o = fmaf(aa.x, wa.x, fmaf(aa.y, wa.y, fmaf(aa.z, wa.z, fmaf(aa.w, wa.w, o))));
      o = fmaf(ab.x, wb.x, fmaf(ab.y, wb.y, fmaf(ab.z, wb.z, fmaf(ab.w, wb.w, o))));
    }
  }
  x1_ws[d*64 + l] = o;
  out_f[d*64 + l] = o;
  bufA[wv*64 + l] = o;
  __syncthreads();
  // --- q MLP on the 4 fresh rows ---
  block_layer_T<64,100,4,true>(wt+T_QWI,  q_bi,     bufA, bufB, tid);
  block_layer_T<100,100,4,true>(wt+T_QWH0, q_bh,     bufB, bufA, tid);
  block_layer_T<100,100,4,true>(wt+T_QWH1, q_bh+100, bufA, bufB, tid);
  block_layer_T<100,18,4,false>(wt+T_QWO,  q_bo,     bufB, bufA, tid);
  int r0 = blockIdx.x*4;
  for (int o2 = tid; o2 < 4*18; o2 += 256) {
    int r = o2 / 18, c = o2 - r*18;
    jsf[(r0+r)*20 + c] = bufA[o2];
  }
}

// ==================== K3: pool_l2 + t2 MLP (4 clusters/block, 128 blocks) ====================
__global__ __launch_bounds__(256) void k3_pool_t2(
    const int* __restrict__ startc2, const int* __restrict__ r2list,
    const float* __restrict__ x1, const float* __restrict__ s1c_raw, const float* __restrict__ c1f,
    const float* __restrict__ wt,
    const float* t2_bi, const float* t2_bh, const float* t2_bo,
    float* __restrict__ x2fc, float* __restrict__ jsf2) {
  int tid = threadIdx.x, wv = tid >> 6, l = tid & 63;
  int s2 = blockIdx.x*4 + wv;
  __shared__ __align__(16) float bufA[4*100];
  __shared__ __align__(16) float bufB[4*100];
  int p0 = startc2[s2], p1 = startc2[s2+1];
  int k = l & 3;
  float acc = 0.f, sc = 0.f, cnt = 0.f;
  for (int p = p0; p < p1; ++p) {
    int r = r2list[p];
    acc += x1[r*64 + l];
    sc  += s1c_raw[r*4 + k];
    cnt += c1f[r];
  }
  float invr = 1.0f / fmaxf((float)(p1 - p0), 1.0f);
  bufA[wv*68 + l] = acc * invr;
  if (l < 4) {
    float mean = sc / fmaxf(cnt, 1.0f);
    bufA[wv*68 + 64 + l] = mean;
    if (l == 0) jsf2[s2*20 + 18] = mean;
    if (l == 1) jsf2[s2*20 + 19] = mean;
  }
  __syncthreads();
  block_layer_T<68,100,4,true>(wt+T_T2WI,  t2_bi,     bufA, bufB, tid);
  block_layer_T<100,100,4,true>(wt+T_T2WH0, t2_bh,     bufB, bufA, tid);
  block_layer_T<100,100,4,true>(wt+T_T2WH1, t2_bh+100, bufA, bufB, tid);
  block_layer_T<100,64,4,false>(wt+T_T2WO,  t2_bo,     bufB, bufA, tid);
  int r0 = blockIdx.x*4;
  for (int o2 = tid; o2 < 4*64; o2 += 256) x2fc[r0*64 + o2] = bufA[o2];
}

// ==================== K4: gc2 + q-MLP(x2) (4 rows/block, 128 blocks) ====================
__global__ __launch_bounds__(256) void k4_gc2_q(
    const int* __restrict__ startE, const int* __restrict__ elist,
    const float* __restrict__ xin,
    const float* __restrict__ wt, const float* bias,
    const float* q_bi, const float* q_bh, const float* q_bo,
    float* __restrict__ out_f, float* __restrict__ jsf2) {
  int tid = threadIdx.x, wv = tid >> 6, l = tid & 63;
  int d = blockIdx.x*4 + wv;
  __shared__ __align__(16) float bufA[4*100];
  __shared__ __align__(16) float bufB[4*100];
  __shared__ __align__(16) float smW[4*128];
  float* sm = smW + wv*128;
  int p0 = startE[d], p1 = startE[d+1];
  float acc = 0.f;
  for (int p = p0; p < p1; ++p) acc += xin[elist[p]*64 + l];
  sm[l]      = acc / fmaxf((float)(p1 - p0), 1.0f);
  sm[64 + l] = xin[d*64 + l];
  __syncthreads();
  float o = bias[l];
  {
    const float4* w1 = reinterpret_cast<const float4*>(wt + T_G2WN + l*64);
    const float4* w2 = reinterpret_cast<const float4*>(wt + T_G2WS + l*64);
    const float4* sa = reinterpret_cast<const float4*>(sm);
    const float4* sb = reinterpret_cast<const float4*>(sm + 64);
    #pragma unroll
    for (int k4 = 0; k4 < 16; ++k4) {
      float4 wa = w1[k4], wb = w2[k4], aa = sa[k4], ab = sb[k4];
      o = fmaf(aa.x, wa.x, fmaf(aa.y, wa.y, fmaf(aa.z, wa.z, fmaf(aa.w, wa.w, o))));
      o = fmaf(ab.x, wb.x, fmaf(ab.y, wb.y, fmaf(ab.z, wb.z, fmaf(ab.w, wb.w, o))));
    }
  }
  out_f[d*64 + l] = o;
  bufA[wv*64 + l] = o;
  __syncthreads();
  block_layer_T<64,100,4,true>(wt+T_QWI,  q_bi,     bufA, bufB, tid);
  block_layer_T<100,100,4,true>(wt+T_QWH0, q_bh,     bufB, bufA, tid);
  block_layer_T<100,100,4,true>(wt+T_QWH1, q_bh+100, bufA, bufB, tid);
  block_layer_T<100,18,4,false>(wt+T_QWO,  q_bo,     bufB, bufA, tid);
  int r0 = blockIdx.x*4;
  for (int o2 = tid; o2 < 4*18; o2 += 256) {
    int r = o2 / 18, c = o2 - r*18;
    jsf2[(r0+r)*20 + c] = bufA[o2];
  }
}

// ---------------- quadratic render (float4 jsf reads) ----------------
__global__ __launch_bounds__(256) void render_kernel(
    const int* __restrict__ cluster1, const int* __restrict__ cluster2,
    const float* __restrict__ jsf1, const float* __restrict__ jsf2,
    float* __restrict__ r1, float* __restrict__ r2) {
  int n = blockIdx.x*256 + threadIdx.x;
  int p = n & 65535, i = p >> 8, j = p & 255;
  float gy = i * (1.0f/256.0f), gx = j * (1.0f/256.0f);
  int s = cluster1[n];
  {
    const float4* f4 = reinterpret_cast<const float4*>(jsf1 + s*20);
    float4 v0 = f4[0], v1 = f4[1], v2 = f4[2], v3 = f4[3], v4 = f4[4];
    float dx = gy - v0.x, dy = gx - v0.y;
    float dxx = dx*dx, dyy = dy*dy, dxy = dx*dy;
    r1[n*3 + 0] = v0.z + v0.w*dx + v1.x*dy + v1.y*dxx + v1.z*dyy + v1.w*dxy;
    r1[n*3 + 1] = v2.x + v2.y*dx + v2.z*dy + v2.w*dxx + v3.x*dyy + v3.y*dxy;
    r1[n*3 + 2] = v3.z + v3.w*dx + v4.x*dy + v4.y*dxx + v4.z*dyy + v4.w*dxy;
  }
  int s2 = cluster2[s];
  {
    const float4* f4 = reinterpret_cast<const float4*>(jsf2 + s2*20);
    float4 v0 = f4[0], v1 = f4[1], v2 = f4[2], v3 = f4[3], v4 = f4[4];
    float dx = gy - v0.x, dy = gx - v0.y;
    float dxx = dx*dx, dyy = dy*dy, dxy = dx*dy;
    r2[n*3 + 0] = v0.z + v0.w*dx + v1.x*dy + v1.y*dxx + v1.z*dyy + v1.w*dxy;
    r2[n*3 + 1] = v2.x + v2.y*dx + v2.z*dy + v2.w*dxx + v3.x*dyy + v3.y*dxy;
    r2[n*3 + 2] = v3.z + v3.w*dx + v4.x*dy + v4.y*dxx + v4.z*dyy + v4.w*dxy;
  }
}

extern "C" void kernel_launch(void* const* d_in, const int* in_sizes, int n_in,
                              void* d_out, int out_size, void* d_ws, size_t ws_size,
                              hipStream_t stream) {
  const float* img    = (const float*)d_in[0];
  const float* conv_w = (const float*)d_in[1];
  const float* conv_b = (const float*)d_in[2];
  const float* t1_wi = (const float*)d_in[3];  const float* t1_bi = (const float*)d_in[4];
  const float* t1_wh = (const float*)d_in[5];  const float* t1_bh = (const float*)d_in[6];
  const float* t1_wo = (const float*)d_in[7];  const float* t1_bo = (const float*)d_in[8];
  const float* t2_wi = (const float*)d_in[9];  const float* t2_bi = (const float*)d_in[10];
  const float* t2_wh = (const float*)d_in[11]; const float* t2_bh = (const float*)d_in[12];
  const float* t2_wo = (const float*)d_in[13]; const float* t2_bo = (const float*)d_in[14];
  const float* q_wi  = (const float*)d_in[15]; const float* q_bi  = (const float*)d_in[16];
  const float* q_wh  = (const float*)d_in[17]; const float* q_bh  = (const float*)d_in[18];
  const float* q_wo  = (const float*)d_in[19]; const float* q_bo  = (const float*)d_in[20];
  const float* gc1_wn = (const float*)d_in[21]; const float* gc1_ws = (const float*)d_in[22];
  const float* gc1_b  = (const float*)d_in[23];
  const float* gc2_wn = (const float*)d_in[24]; const float* gc2_ws = (const float*)d_in[25];
  const float* gc2_b  = (const float*)d_in[26];
  const int* cluster1 = (const int*)d_in[27];
  const int* cluster2 = (const int*)d_in[28];
  const int* edges1   = (const int*)d_in[29];
  const int* edges2   = (const int*)d_in[30];

  float* ws = (float*)d_ws;
  int*   wsI = (int*)d_ws;
  float* wt  = ws + OFF_WT;
  float* out  = (float*)d_out;
  float* o_r1 = out;
  float* o_r2 = out + 786432;
  float* o_x1 = out + 1572864;
  float* o_x2 = out + 1835008;

  // prep: zero histograms + transpose all weights (one kernel, no memset node)
  prep<<<(ZEROI_END + WT_END + 255)/256, 256, 0, stream>>>(
      t1_wi, t1_wh, t1_wo, t2_wi, t2_wh, t2_wo, q_wi, q_wh, q_wo,
      gc1_wn, gc1_ws, gc2_wn, gc2_ws, wsI, wt);

  constexpr int TOTW = NPIX + M1C + E1C + E2C;   // 339968, /256 = 1328 exact
  build_hist<<<TOTW/256, 256, 0, stream>>>(cluster1, cluster2, edges1, edges2, wsI);
  scan_kernel<<<4, 1024, 0, stream>>>(wsI);
  scatter_all<<<TOTW/256, 256, 0, stream>>>(cluster1, cluster2, edges1, edges2, wsI);

  // K1: conv-linearity gather + t1 MLP
  k1_gather_t1<<<M1C/4, 256, 0, stream>>>(img, conv_w, conv_b,
      wsI+IOFF_ST1, wsI+IOFF_PLIST, wt,
      t1_bi, t1_bh, t1_bo,
      ws+OFF_X1FC, ws+OFF_S1CR, ws+OFF_C1, ws+OFF_JSF1);

  // K2: graph conv 1 + q MLP on x1 rows
  k2_gc1_q<<<M1C/4, 256, 0, stream>>>(wsI+IOFF_STE1, wsI+IOFF_E1L, ws+OFF_X1FC,
      wt, gc1_b, q_bi, q_bh, q_bo,
      ws+OFF_X1, o_x1, ws+OFF_JSF1);

  // K3: level-2 pooling + t2 MLP
  k3_pool_t2<<<M2C/4, 256, 0, stream>>>(wsI+IOFF_STC2, wsI+IOFF_R2L,
      ws+OFF_X1, ws+OFF_S1CR, ws+OFF_C1, wt,
      t2_bi, t2_bh, t2_bo,
      ws+OFF_X2FC, ws+OFF_JSF2);

  // K4: graph conv 2 + q MLP on x2 rows
  k4_gc2_q<<<M2C/4, 256, 0, stream>>>(wsI+IOFF_STE2, wsI+IOFF_E2L, ws+OFF_X2FC,
      wt, gc2_b, q_bi, q_bh, q_bo,
      o_x2, ws+OFF_JSF2);

  // render
  render_kernel<<<NPIX/256, 256, 0, stream>>>(cluster1, cluster2, ws+OFF_JSF1, ws+OFF_JSF2, o_r1, o_r2);
}

// Round 13
// 169.879 us; speedup vs baseline: 1.2050x; 1.2050x over previous
//
#include <hip/hip_runtime.h>

#define NPIX 262144   // B*H*H = 4*256*256
#define M1C 4096
#define M2C 512
#define E1C 65536
#define E2C 8192

// ---- workspace layout (4-byte element offsets) ----
// zeroed region (int histograms only):
constexpr int IOFF_H1   = 0;                 // 4096
constexpr int IOFF_HC2  = IOFF_H1  + M1C;    // 512
constexpr int IOFF_HE1  = IOFF_HC2 + M2C;    // 4096
constexpr int IOFF_HE2  = IOFF_HE1 + M1C;    // 512
constexpr int ZEROI_END = IOFF_HE2 + M2C;    // 9216 ints

constexpr int IOFF_ST1   = ZEROI_END;              // 4097
constexpr int IOFF_CU1   = IOFF_ST1  + M1C + 1;    // 4096
constexpr int IOFF_STC2  = IOFF_CU1  + M1C;        // 513
constexpr int IOFF_CUC2  = IOFF_STC2 + M2C + 1;    // 512
constexpr int IOFF_STE1  = IOFF_CUC2 + M2C;        // 4097
constexpr int IOFF_CUE1  = IOFF_STE1 + M1C + 1;    // 4096
constexpr int IOFF_STE2  = IOFF_CUE1 + M1C;        // 513
constexpr int IOFF_CUE2  = IOFF_STE2 + M2C + 1;    // 512
constexpr int IOFF_PLIST = IOFF_CUE2 + M2C;        // 262144 (pixels sorted by cluster)
constexpr int IOFF_R2L   = IOFF_PLIST + NPIX;      // 4096
constexpr int IOFF_E1L   = IOFF_R2L + M1C;         // 65536
constexpr int IOFF_E2L   = IOFF_E1L + E1C;         // 8192
constexpr int IEND0      = IOFF_E2L + E2C;
constexpr int IEND       = (IEND0 + 3) & ~3;       // 16B-align float region

// float scratch:
constexpr int OFF_S1CR  = IEND;                    // 4096*4 raw coord sums
constexpr int OFF_C1    = OFF_S1CR + M1C*4;        // 4096 counts
constexpr int OFF_X1FC  = OFF_C1 + M1C;            // 4096*64 (t1 out, gc1 in)
constexpr int OFF_X1    = OFF_X1FC + M1C*64;       // 4096*64 (gc1 out, pool in)
constexpr int OFF_X2FC  = OFF_X1 + M1C*64;         // 512*64  (t2 out, gc2 in)
constexpr int OFF_JSF1  = OFF_X2FC + M2C*64;       // 4096*20 (80B rows, 16B-aligned)
constexpr int OFF_JSF2  = OFF_JSF1 + M1C*20;       // 512*20
constexpr int OFF_PAD   = OFF_JSF2 + M2C*20;       // 4*258*258*3 = 798768 zero-padded img

#define PAD_ROW   774        // 258*3
#define PAD_BATCH 199692     // 258*774
#define PAD_TOT   266256     // 4*258*258

// ---------------- workspace zeroing ----------------
__global__ __launch_bounds__(256) void zero_ws(int* __restrict__ wsI) {
  int i = blockIdx.x*256 + threadIdx.x;
  if (i < ZEROI_END) wsI[i] = 0;
}

// ---------------- zero-padded image copy: [4][258][258][3], border = 0 ----------------
__global__ __launch_bounds__(256) void pad_img(
    const float* __restrict__ img, float* __restrict__ pad) {
  int idx = blockIdx.x*256 + threadIdx.x;
  if (idx >= PAD_TOT) return;
  int b = idx / 66564, r = idx - b*66564;
  int py = r / 258, px = r - py*258;
  float v0 = 0.f, v1 = 0.f, v2 = 0.f;
  int y = py - 1, x = px - 1;
  if ((unsigned)y < 256u && (unsigned)x < 256u) {
    const float* s = img + (size_t)(((b << 16) + (y << 8) + x) * 3);
    v0 = s[0]; v1 = s[1]; v2 = s[2];
  }
  float* d = pad + (size_t)idx*3;
  d[0] = v0; d[1] = v1; d[2] = v2;
}

// ---------------- fused histograms ----------------
__global__ __launch_bounds__(256) void build_hist(
    const int* __restrict__ c1, const int* __restrict__ c2,
    const int* __restrict__ e1, const int* __restrict__ e2, int* __restrict__ wsI) {
  int i = blockIdx.x*256 + threadIdx.x;
  if (i < NPIX) {
    atomicAdd(&wsI[IOFF_H1 + c1[i]], 1);
  } else if (i < NPIX + M1C) {
    atomicAdd(&wsI[IOFF_HC2 + c2[i - NPIX]], 1);
  } else if (i < NPIX + M1C + E1C) {
    int e = i - NPIX - M1C;
    atomicAdd(&wsI[IOFF_HE1 + e1[E1C + e]], 1);
  } else {
    int e = i - NPIX - M1C - E1C;
    atomicAdd(&wsI[IOFF_HE2 + e2[E2C + e]], 1);
  }
}

// ---------------- exclusive scan, one block per histogram ----------------
__global__ __launch_bounds__(1024) void scan_kernel(int* __restrict__ wsI) {
  const int* hist; int* start; int* curs; int n;
  if (blockIdx.x == 0)      { hist = wsI+IOFF_H1;  start = wsI+IOFF_ST1;  curs = wsI+IOFF_CU1;  n = M1C; }
  else if (blockIdx.x == 1) { hist = wsI+IOFF_HC2; start = wsI+IOFF_STC2; curs = wsI+IOFF_CUC2; n = M2C; }
  else if (blockIdx.x == 2) { hist = wsI+IOFF_HE1; start = wsI+IOFF_STE1; curs = wsI+IOFF_CUE1; n = M1C; }
  else                      { hist = wsI+IOFF_HE2; start = wsI+IOFF_STE2; curs = wsI+IOFF_CUE2; n = M2C; }
  __shared__ int part[1024];
  int t = threadIdx.x, base = t*4, sum = 0;
  int loc0, loc1, loc2, loc3;
  loc0 = sum; sum += (base+0 < n) ? hist[base+0] : 0;
  loc1 = sum; sum += (base+1 < n) ? hist[base+1] : 0;
  loc2 = sum; sum += (base+2 < n) ? hist[base+2] : 0;
  loc3 = sum; sum += (base+3 < n) ? hist[base+3] : 0;
  part[t] = sum;
  __syncthreads();
  for (int off = 1; off < 1024; off <<= 1) {
    int v = (t >= off) ? part[t-off] : 0;
    __syncthreads();
    part[t] += v;
    __syncthreads();
  }
  int excl = (t == 0) ? 0 : part[t-1];
  if (base+0 < n) { start[base+0] = excl+loc0; curs[base+0] = excl+loc0; }
  if (base+1 < n) { start[base+1] = excl+loc1; curs[base+1] = excl+loc1; }
  if (base+2 < n) { start[base+2] = excl+loc2; curs[base+2] = excl+loc2; }
  if (base+3 < n) { start[base+3] = excl+loc3; curs[base+3] = excl+loc3; }
  if (t == 0) start[n] = part[1023];
}

// ---------------- fused scatter into bins ----------------
__global__ __launch_bounds__(256) void scatter_all(
    const int* __restrict__ c1, const int* __restrict__ c2,
    const int* __restrict__ e1, const int* __restrict__ e2, int* __restrict__ wsI) {
  int i = blockIdx.x*256 + threadIdx.x;
  if (i < NPIX) {
    int s = c1[i];
    int pos = atomicAdd(&wsI[IOFF_CU1 + s], 1);
    wsI[IOFF_PLIST + pos] = i;
  } else if (i < NPIX + M1C) {
    int r = i - NPIX;
    int pos = atomicAdd(&wsI[IOFF_CUC2 + c2[r]], 1);
    wsI[IOFF_R2L + pos] = r;
  } else if (i < NPIX + M1C + E1C) {
    int e = i - NPIX - M1C;
    int pos = atomicAdd(&wsI[IOFF_CUE1 + e1[E1C + e]], 1);
    wsI[IOFF_E1L + pos] = e1[e];
  } else {
    int e = i - NPIX - M1C - E1C;
    int pos = atomicAdd(&wsI[IOFF_CUE2 + e2[E2C + e]], 1);
    wsI[IOFF_E2L + pos] = e2[e];
  }
}

// ---------------- block-level dense layer (coalesced W loads across lanes) ----------------
template<int NIN, int NOUT, int R, bool RELU>
__device__ __forceinline__ void block_layer(
    const float* __restrict__ W, const float* __restrict__ B,
    const float* __restrict__ actIn, float* __restrict__ actOut, int tid) {
  constexpr int NG  = 256 / NOUT;
  constexpr int RPT = (R + NG - 1) / NG;
  static_assert(NIN % 4 == 0, "NIN must be multiple of 4");
  int c  = tid % NOUT;
  int rg = tid / NOUT;
  if (rg < NG) {
    float acc[RPT];
    #pragma unroll
    for (int i = 0; i < RPT; ++i) acc[i] = 0.f;
    #pragma unroll 4
    for (int kc = 0; kc < NIN/4; ++kc) {
      float w0 = W[(kc*4+0)*NOUT + c];
      float w1 = W[(kc*4+1)*NOUT + c];
      float w2 = W[(kc*4+2)*NOUT + c];
      float w3 = W[(kc*4+3)*NOUT + c];
      #pragma unroll
      for (int i = 0; i < RPT; ++i) {
        int r = rg + i*NG;
        if (r < R) {
          float4 a = *reinterpret_cast<const float4*>(actIn + r*NIN + kc*4);
          acc[i] = fmaf(a.x, w0, fmaf(a.y, w1, fmaf(a.z, w2, fmaf(a.w, w3, acc[i]))));
        }
      }
    }
    float b = B[c];
    #pragma unroll
    for (int i = 0; i < RPT; ++i) {
      int r = rg + i*NG;
      if (r < R) {
        float v = acc[i] + b;
        actOut[r*NOUT + c] = RELU ? fmaxf(v, 0.f) : v;
      }
    }
  }
  __syncthreads();
}

// ==================== K1: padded-img gather + t1 MLP (4 clusters/block) ====================
__global__ __launch_bounds__(256) void k1_gather_t1(
    const float* __restrict__ pad, const float* __restrict__ cw, const float* __restrict__ cb,
    const int* __restrict__ start, const int* __restrict__ plist,
    const float* t1_wi, const float* t1_bi, const float* t1_wh, const float* t1_bh,
    const float* t1_wo, const float* t1_bo,
    float* __restrict__ x1fc, float* __restrict__ s1c_raw, float* __restrict__ c1f,
    float* __restrict__ jsf1) {
  int tid = threadIdx.x, wv = tid >> 6, l = tid & 63;
  int s = blockIdx.x*4 + wv;
  __shared__ __align__(16) float bufA[4*100];
  __shared__ __align__(16) float bufB[4*100];
  // --- gather phase (wave per cluster), single unguarded path over padded img ---
  int p0 = start[s], p1 = start[s+1];
  int count = p1 - p0;
  float ps[27];
  #pragma unroll
  for (int k = 0; k < 27; ++k) ps[k] = 0.f;
  float sy = 0.f, sx = 0.f, syy = 0.f, sxx = 0.f;
  for (int p = p0 + l; p < p1; p += 64) {
    int n = plist[p];
    int b = n >> 16, pp = n & 65535, i = pp >> 8, j = pp & 255;
    const float* pb = pad + (size_t)b*PAD_BATCH + i*PAD_ROW + j*3;
    #pragma unroll
    for (int di = 0; di < 3; ++di) {
      const float* rp = pb + di*PAD_ROW;
      #pragma unroll
      for (int t = 0; t < 9; ++t) ps[di*9 + t] += rp[t];
    }
    float yi = i * (1.0f/256.0f), xj = j * (1.0f/256.0f);
    sy += yi; sx += xj; syy += yi*yi; sxx += xj*xj;
  }
  #pragma unroll
  for (int m = 1; m < 64; m <<= 1) {
    #pragma unroll
    for (int k = 0; k < 27; ++k) ps[k] += __shfl_xor(ps[k], m);
    sy  += __shfl_xor(sy,  m);
    sx  += __shfl_xor(sx,  m);
    syy += __shfl_xor(syy, m);
    sxx += __shfl_xor(sxx, m);
  }
  float inv = 1.0f / fmaxf((float)count, 1.0f);
  float o = cb[l];
  #pragma unroll
  for (int k = 0; k < 27; ++k) o = fmaf(ps[k]*inv, cw[k*64 + l], o);
  bufA[wv*68 + l] = count ? o : 0.f;                // x1cat row lives in LDS only
  if (l == 0) {
    bufA[wv*68 + 64] = sy*inv;
    bufA[wv*68 + 65] = sx*inv;
    bufA[wv*68 + 66] = syy*inv;
    bufA[wv*68 + 67] = sxx*inv;
    s1c_raw[s*4+0] = sy; s1c_raw[s*4+1] = sx;
    s1c_raw[s*4+2] = syy; s1c_raw[s*4+3] = sxx;
    jsf1[s*20 + 18] = sy*inv;
    jsf1[s*20 + 19] = sx*inv;
    c1f[s] = (float)count;
  }
  __syncthreads();
  // --- t1 MLP on the block's 4 rows ---
  block_layer<68,100,4,true>(t1_wi, t1_bi, bufA, bufB, tid);
  block_layer<100,100,4,true>(t1_wh, t1_bh, bufB, bufA, tid);
  block_layer<100,100,4,true>(t1_wh+10000, t1_bh+100, bufA, bufB, tid);
  block_layer<100,64,4,false>(t1_wo, t1_bo, bufB, bufA, tid);
  int r0 = blockIdx.x*4;
  for (int o2 = tid; o2 < 4*64; o2 += 256) x1fc[r0*64 + o2] = bufA[o2];
}

// ---------------- edge mean with 4-wide pipelined accumulation ----------------
__device__ __forceinline__ float edge_mean(
    const int* __restrict__ elist, const float* __restrict__ xin,
    int p0, int p1, int l) {
  float a0 = 0.f, a1 = 0.f, a2 = 0.f, a3 = 0.f;
  int p = p0;
  for (; p + 3 < p1; p += 4) {
    int s0 = elist[p], s1 = elist[p+1], s2 = elist[p+2], s3 = elist[p+3];
    a0 += xin[s0*64 + l];
    a1 += xin[s1*64 + l];
    a2 += xin[s2*64 + l];
    a3 += xin[s3*64 + l];
  }
  for (; p < p1; ++p) a0 += xin[elist[p]*64 + l];
  return ((a0 + a1) + (a2 + a3)) / fmaxf((float)(p1 - p0), 1.0f);
}

// ==================== K2: gc1 + q-MLP(x1) (4 rows/block, 1024 blocks) ====================
__global__ __launch_bounds__(256) void k2_gc1_q(
    const int* __restrict__ startE, const int* __restrict__ elist,
    const float* __restrict__ xin,
    const float* wn, const float* wsf, const float* bias,
    const float* q_wi, const float* q_bi, const float* q_wh, const float* q_bh,
    const float* q_wo, const float* q_bo,
    float* __restrict__ x1_ws, float* __restrict__ out_f, float* __restrict__ jsf) {
  int tid = threadIdx.x, wv = tid >> 6, l = tid & 63;
  int d = blockIdx.x*4 + wv;
  __shared__ __align__(16) float bufA[4*100];
  __shared__ __align__(16) float bufB[4*100];
  __shared__ float smW[4*128];
  float* sm = smW + wv*128;
  // --- graph conv ---
  sm[l]      = edge_mean(elist, xin, startE[d], startE[d+1], l);
  sm[64 + l] = xin[d*64 + l];
  __syncthreads();
  float o = bias[l];
  #pragma unroll 8
  for (int k = 0; k < 64; ++k)
    o += sm[k]*wn[k*64 + l] + sm[64 + k]*wsf[k*64 + l];
  x1_ws[d*64 + l] = o;
  out_f[d*64 + l] = o;
  bufA[wv*64 + l] = o;
  __syncthreads();
  // --- q MLP on the 4 fresh rows ---
  block_layer<64,100,4,true>(q_wi, q_bi, bufA, bufB, tid);
  block_layer<100,100,4,true>(q_wh, q_bh, bufB, bufA, tid);
  block_layer<100,100,4,true>(q_wh+10000, q_bh+100, bufA, bufB, tid);
  block_layer<100,18,4,false>(q_wo, q_bo, bufB, bufA, tid);
  int r0 = blockIdx.x*4;
  for (int o2 = tid; o2 < 4*18; o2 += 256) {
    int r = o2 / 18, c = o2 - r*18;
    jsf[(r0+r)*20 + c] = bufA[o2];
  }
}

// ==================== K3: pool_l2 + t2 MLP (4 clusters/block, 128 blocks) ====================
__global__ __launch_bounds__(256) void k3_pool_t2(
    const int* __restrict__ startc2, const int* __restrict__ r2list,
    const float* __restrict__ x1, const float* __restrict__ s1c_raw, const float* __restrict__ c1f,
    const float* t2_wi, const float* t2_bi, const float* t2_wh, const float* t2_bh,
    const float* t2_wo, const float* t2_bo,
    float* __restrict__ x2fc, float* __restrict__ jsf2) {
  int tid = threadIdx.x, wv = tid >> 6, l = tid & 63;
  int s2 = blockIdx.x*4 + wv;
  __shared__ __align__(16) float bufA[4*100];
  __shared__ __align__(16) float bufB[4*100];
  int p0 = startc2[s2], p1 = startc2[s2+1];
  int k = l & 3;
  float acc = 0.f, sc = 0.f, cnt = 0.f;
  for (int p = p0; p < p1; ++p) {
    int r = r2list[p];
    acc += x1[r*64 + l];
    sc  += s1c_raw[r*4 + k];
    cnt += c1f[r];
  }
  float invr = 1.0f / fmaxf((float)(p1 - p0), 1.0f);
  bufA[wv*68 + l] = acc * invr;
  if (l < 4) {
    float mean = sc / fmaxf(cnt, 1.0f);
    bufA[wv*68 + 64 + l] = mean;
    if (l == 0) jsf2[s2*20 + 18] = mean;
    if (l == 1) jsf2[s2*20 + 19] = mean;
  }
  __syncthreads();
  block_layer<68,100,4,true>(t2_wi, t2_bi, bufA, bufB, tid);
  block_layer<100,100,4,true>(t2_wh, t2_bh, bufB, bufA, tid);
  block_layer<100,100,4,true>(t2_wh+10000, t2_bh+100, bufA, bufB, tid);
  block_layer<100,64,4,false>(t2_wo, t2_bo, bufB, bufA, tid);
  int r0 = blockIdx.x*4;
  for (int o2 = tid; o2 < 4*64; o2 += 256) x2fc[r0*64 + o2] = bufA[o2];
}

// ==================== K4: gc2 + q-MLP(x2) (4 rows/block, 128 blocks) ====================
__global__ __launch_bounds__(256) void k4_gc2_q(
    const int* __restrict__ startE, const int* __restrict__ elist,
    const float* __restrict__ xin,
    const float* wn, const float* wsf, const float* bias,
    const float* q_wi, const float* q_bi, const float* q_wh, const float* q_bh,
    const float* q_wo, const float* q_bo,
    float* __restrict__ out_f, float* __restrict__ jsf2) {
  int tid = threadIdx.x, wv = tid >> 6, l = tid & 63;
  int d = blockIdx.x*4 + wv;
  __shared__ __align__(16) float bufA[4*100];
  __shared__ __align__(16) float bufB[4*100];
  __shared__ float smW[4*128];
  float* sm = smW + wv*128;
  sm[l]      = edge_mean(elist, xin, startE[d], startE[d+1], l);
  sm[64 + l] = xin[d*64 + l];
  __syncthreads();
  float o = bias[l];
  #pragma unroll 8
  for (int k = 0; k < 64; ++k)
    o += sm[k]*wn[k*64 + l] + sm[64 + k]*wsf[k*64 + l];
  out_f[d*64 + l] = o;
  bufA[wv*64 + l] = o;
  __syncthreads();
  block_layer<64,100,4,true>(q_wi, q_bi, bufA, bufB, tid);
  block_layer<100,100,4,true>(q_wh, q_bh, bufB, bufA, tid);
  block_layer<100,100,4,true>(q_wh+10000, q_bh+100, bufA, bufB, tid);
  block_layer<100,18,4,false>(q_wo, q_bo, bufB, bufA, tid);
  int r0 = blockIdx.x*4;
  for (int o2 = tid; o2 < 4*18; o2 += 256) {
    int r = o2 / 18, c = o2 - r*18;
    jsf2[(r0+r)*20 + c] = bufA[o2];
  }
}

// ---------------- quadratic render (float4 jsf reads) ----------------
__global__ __launch_bounds__(256) void render_kernel(
    const int* __restrict__ cluster1, const int* __restrict__ cluster2,
    const float* __restrict__ jsf1, const float* __restrict__ jsf2,
    float* __restrict__ r1, float* __restrict__ r2) {
  int n = blockIdx.x*256 + threadIdx.x;
  int p = n & 65535, i = p >> 8, j = p & 255;
  float gy = i * (1.0f/256.0f), gx = j * (1.0f/256.0f);
  int s = cluster1[n];
  {
    const float4* f4 = reinterpret_cast<const float4*>(jsf1 + s*20);
    float4 v0 = f4[0], v1 = f4[1], v2 = f4[2], v3 = f4[3], v4 = f4[4];
    float dx = gy - v0.x, dy = gx - v0.y;
    float dxx = dx*dx, dyy = dy*dy, dxy = dx*dy;
    r1[n*3 + 0] = v0.z + v0.w*dx + v1.x*dy + v1.y*dxx + v1.z*dyy + v1.w*dxy;
    r1[n*3 + 1] = v2.x + v2.y*dx + v2.z*dy + v2.w*dxx + v3.x*dyy + v3.y*dxy;
    r1[n*3 + 2] = v3.z + v3.w*dx + v4.x*dy + v4.y*dxx + v4.z*dyy + v4.w*dxy;
  }
  int s2 = cluster2[s];
  {
    const float4* f4 = reinterpret_cast<const float4*>(jsf2 + s2*20);
    float4 v0 = f4[0], v1 = f4[1], v2 = f4[2], v3 = f4[3], v4 = f4[4];
    float dx = gy - v0.x, dy = gx - v0.y;
    float dxx = dx*dx, dyy = dy*dy, dxy = dx*dy;
    r2[n*3 + 0] = v0.z + v0.w*dx + v1.x*dy + v1.y*dxx + v1.z*dyy + v1.w*dxy;
    r2[n*3 + 1] = v2.x + v2.y*dx + v2.z*dy + v2.w*dxx + v3.x*dyy + v3.y*dxy;
    r2[n*3 + 2] = v3.z + v3.w*dx + v4.x*dy + v4.y*dxx + v4.z*dyy + v4.w*dxy;
  }
}

extern "C" void kernel_launch(void* const* d_in, const int* in_sizes, int n_in,
                              void* d_out, int out_size, void* d_ws, size_t ws_size,
                              hipStream_t stream) {
  const float* img    = (const float*)d_in[0];
  const float* conv_w = (const float*)d_in[1];
  const float* conv_b = (const float*)d_in[2];
  const float* t1_wi = (const float*)d_in[3];  const float* t1_bi = (const float*)d_in[4];
  const float* t1_wh = (const float*)d_in[5];  const float* t1_bh = (const float*)d_in[6];
  const float* t1_wo = (const float*)d_in[7];  const float* t1_bo = (const float*)d_in[8];
  const float* t2_wi = (const float*)d_in[9];  const float* t2_bi = (const float*)d_in[10];
  const float* t2_wh = (const float*)d_in[11]; const float* t2_bh = (const float*)d_in[12];
  const float* t2_wo = (const float*)d_in[13]; const float* t2_bo = (const float*)d_in[14];
  const float* q_wi  = (const float*)d_in[15]; const float* q_bi  = (const float*)d_in[16];
  const float* q_wh  = (const float*)d_in[17]; const float* q_bh  = (const float*)d_in[18];
  const float* q_wo  = (const float*)d_in[19]; const float* q_bo  = (const float*)d_in[20];
  const float* gc1_wn = (const float*)d_in[21]; const float* gc1_ws = (const float*)d_in[22];
  const float* gc1_b  = (const float*)d_in[23];
  const float* gc2_wn = (const float*)d_in[24]; const float* gc2_ws = (const float*)d_in[25];
  const float* gc2_b  = (const float*)d_in[26];
  const int* cluster1 = (const int*)d_in[27];
  const int* cluster2 = (const int*)d_in[28];
  const int* edges1   = (const int*)d_in[29];
  const int* edges2   = (const int*)d_in[30];

  float* ws = (float*)d_ws;
  int*   wsI = (int*)d_ws;
  float* out  = (float*)d_out;
  float* o_r1 = out;
  float* o_r2 = out + 786432;
  float* o_x1 = out + 1572864;
  float* o_x2 = out + 1835008;

  // zero the int histograms
  zero_ws<<<(ZEROI_END + 255)/256, 256, 0, stream>>>(wsI);
  // build zero-padded image (removes all per-tap guards from k1)
  pad_img<<<(PAD_TOT + 255)/256, 256, 0, stream>>>(img, ws + OFF_PAD);

  constexpr int TOTW = NPIX + M1C + E1C + E2C;   // 339968, /256 = 1328 exact
  build_hist<<<TOTW/256, 256, 0, stream>>>(cluster1, cluster2, edges1, edges2, wsI);
  scan_kernel<<<4, 1024, 0, stream>>>(wsI);
  scatter_all<<<TOTW/256, 256, 0, stream>>>(cluster1, cluster2, edges1, edges2, wsI);

  // K1: padded-img gather + t1 MLP (x1cat never hits global)
  k1_gather_t1<<<M1C/4, 256, 0, stream>>>(ws + OFF_PAD, conv_w, conv_b,
      wsI+IOFF_ST1, wsI+IOFF_PLIST,
      t1_wi, t1_bi, t1_wh, t1_bh, t1_wo, t1_bo,
      ws+OFF_X1FC, ws+OFF_S1CR, ws+OFF_C1, ws+OFF_JSF1);

  // K2: graph conv 1 + q MLP on x1 rows
  k2_gc1_q<<<M1C/4, 256, 0, stream>>>(wsI+IOFF_STE1, wsI+IOFF_E1L, ws+OFF_X1FC,
      gc1_wn, gc1_ws, gc1_b,
      q_wi, q_bi, q_wh, q_bh, q_wo, q_bo,
      ws+OFF_X1, o_x1, ws+OFF_JSF1);

  // K3: level-2 pooling + t2 MLP
  k3_pool_t2<<<M2C/4, 256, 0, stream>>>(wsI+IOFF_STC2, wsI+IOFF_R2L,
      ws+OFF_X1, ws+OFF_S1CR, ws+OFF_C1,
      t2_wi, t2_bi, t2_wh, t2_bh, t2_wo, t2_bo,
      ws+OFF_X2FC, ws+OFF_JSF2);

  // K4: graph conv 2 + q MLP on x2 rows
  k4_gc2_q<<<M2C/4, 256, 0, stream>>>(wsI+IOFF_STE2, wsI+IOFF_E2L, ws+OFF_X2FC,
      gc2_wn, gc2_ws, gc2_b,
      q_wi, q_bi, q_wh, q_bh, q_wo, q_bo,
      o_x2, ws+OFF_JSF2);

  // render
  render_kernel<<<NPIX/256, 256, 0, stream>>>(cluster1, cluster2, ws+OFF_JSF1, ws+OFF_JSF2, o_r1, o_r2);
}

// Round 14
// 167.938 us; speedup vs baseline: 1.2189x; 1.0116x over previous
//
#include <hip/hip_runtime.h>

#define NPIX 262144   // B*H*H = 4*256*256
#define M1C 4096
#define M2C 512
#define E1C 65536
#define E2C 8192

// ---- workspace layout (4-byte element offsets) ----
// zeroed region (int histograms only):
constexpr int IOFF_H1   = 0;                 // 4096
constexpr int IOFF_HC2  = IOFF_H1  + M1C;    // 512
constexpr int IOFF_HE1  = IOFF_HC2 + M2C;    // 4096
constexpr int IOFF_HE2  = IOFF_HE1 + M1C;    // 512
constexpr int ZEROI_END = IOFF_HE2 + M2C;    // 9216 ints

constexpr int IOFF_ST1   = ZEROI_END;              // 4097
constexpr int IOFF_CU1   = IOFF_ST1  + M1C + 1;    // 4096
constexpr int IOFF_STC2  = IOFF_CU1  + M1C;        // 513
constexpr int IOFF_CUC2  = IOFF_STC2 + M2C + 1;    // 512
constexpr int IOFF_STE1  = IOFF_CUC2 + M2C;        // 4097
constexpr int IOFF_CUE1  = IOFF_STE1 + M1C + 1;    // 4096
constexpr int IOFF_STE2  = IOFF_CUE1 + M1C;        // 513
constexpr int IOFF_CUE2  = IOFF_STE2 + M2C + 1;    // 512
constexpr int IOFF_PLIST = IOFF_CUE2 + M2C;        // 262144 (pixels sorted by cluster)
constexpr int IOFF_R2L   = IOFF_PLIST + NPIX;      // 4096
constexpr int IOFF_E1L   = IOFF_R2L + M1C;         // 65536
constexpr int IOFF_E2L   = IOFF_E1L + E1C;         // 8192
constexpr int IEND0      = IOFF_E2L + E2C;
constexpr int IEND       = (IEND0 + 3) & ~3;       // 16B-align float region

// float scratch:
constexpr int OFF_S1CR  = IEND;                    // 4096*4 raw coord sums
constexpr int OFF_C1    = OFF_S1CR + M1C*4;        // 4096 counts
constexpr int OFF_X1FC  = OFF_C1 + M1C;            // 4096*64 (t1 out, gc1 in)
constexpr int OFF_X1    = OFF_X1FC + M1C*64;       // 4096*64 (gc1 out, pool in)
constexpr int OFF_X2FC  = OFF_X1 + M1C*64;         // 512*64  (t2 out, gc2 in)
constexpr int OFF_JSF1  = OFF_X2FC + M2C*64;       // 4096*20 (80B rows, 16B-aligned)
constexpr int OFF_JSF2  = OFF_JSF1 + M1C*20;       // 512*20
constexpr int OFF_PAD   = OFF_JSF2 + M2C*20;       // 4*258*258*3 zero-padded img

#define PAD_ROW   774        // 258*3
#define PAD_BATCH 199692     // 258*774
#define PAD_TOT   266256     // 4*258*258

// ---------------- prep: zero histograms + build zero-padded image (one launch) ----------------
__global__ __launch_bounds__(256) void prep(
    const float* __restrict__ img, float* __restrict__ pad, int* __restrict__ wsI) {
  int idx = blockIdx.x*256 + threadIdx.x;
  if (idx < ZEROI_END) wsI[idx] = 0;
  if (idx >= PAD_TOT) return;
  int b = idx / 66564, r = idx - b*66564;
  int py = r / 258, px = r - py*258;
  float v0 = 0.f, v1 = 0.f, v2 = 0.f;
  int y = py - 1, x = px - 1;
  if ((unsigned)y < 256u && (unsigned)x < 256u) {
    const float* s = img + (size_t)(((b << 16) + (y << 8) + x) * 3);
    v0 = s[0]; v1 = s[1]; v2 = s[2];
  }
  float* d = pad + (size_t)idx*3;
  d[0] = v0; d[1] = v1; d[2] = v2;
}

// ---------------- fused histograms ----------------
__global__ __launch_bounds__(256) void build_hist(
    const int* __restrict__ c1, const int* __restrict__ c2,
    const int* __restrict__ e1, const int* __restrict__ e2, int* __restrict__ wsI) {
  int i = blockIdx.x*256 + threadIdx.x;
  if (i < NPIX) {
    atomicAdd(&wsI[IOFF_H1 + c1[i]], 1);
  } else if (i < NPIX + M1C) {
    atomicAdd(&wsI[IOFF_HC2 + c2[i - NPIX]], 1);
  } else if (i < NPIX + M1C + E1C) {
    int e = i - NPIX - M1C;
    atomicAdd(&wsI[IOFF_HE1 + e1[E1C + e]], 1);
  } else {
    int e = i - NPIX - M1C - E1C;
    atomicAdd(&wsI[IOFF_HE2 + e2[E2C + e]], 1);
  }
}

// ---------------- exclusive scan, one block per histogram ----------------
__global__ __launch_bounds__(1024) void scan_kernel(int* __restrict__ wsI) {
  const int* hist; int* start; int* curs; int n;
  if (blockIdx.x == 0)      { hist = wsI+IOFF_H1;  start = wsI+IOFF_ST1;  curs = wsI+IOFF_CU1;  n = M1C; }
  else if (blockIdx.x == 1) { hist = wsI+IOFF_HC2; start = wsI+IOFF_STC2; curs = wsI+IOFF_CUC2; n = M2C; }
  else if (blockIdx.x == 2) { hist = wsI+IOFF_HE1; start = wsI+IOFF_STE1; curs = wsI+IOFF_CUE1; n = M1C; }
  else                      { hist = wsI+IOFF_HE2; start = wsI+IOFF_STE2; curs = wsI+IOFF_CUE2; n = M2C; }
  __shared__ int part[1024];
  int t = threadIdx.x, base = t*4, sum = 0;
  int loc0, loc1, loc2, loc3;
  loc0 = sum; sum += (base+0 < n) ? hist[base+0] : 0;
  loc1 = sum; sum += (base+1 < n) ? hist[base+1] : 0;
  loc2 = sum; sum += (base+2 < n) ? hist[base+2] : 0;
  loc3 = sum; sum += (base+3 < n) ? hist[base+3] : 0;
  part[t] = sum;
  __syncthreads();
  for (int off = 1; off < 1024; off <<= 1) {
    int v = (t >= off) ? part[t-off] : 0;
    __syncthreads();
    part[t] += v;
    __syncthreads();
  }
  int excl = (t == 0) ? 0 : part[t-1];
  if (base+0 < n) { start[base+0] = excl+loc0; curs[base+0] = excl+loc0; }
  if (base+1 < n) { start[base+1] = excl+loc1; curs[base+1] = excl+loc1; }
  if (base+2 < n) { start[base+2] = excl+loc2; curs[base+2] = excl+loc2; }
  if (base+3 < n) { start[base+3] = excl+loc3; curs[base+3] = excl+loc3; }
  if (t == 0) start[n] = part[1023];
}

// ---------------- fused scatter into bins ----------------
__global__ __launch_bounds__(256) void scatter_all(
    const int* __restrict__ c1, const int* __restrict__ c2,
    const int* __restrict__ e1, const int* __restrict__ e2, int* __restrict__ wsI) {
  int i = blockIdx.x*256 + threadIdx.x;
  if (i < NPIX) {
    int s = c1[i];
    int pos = atomicAdd(&wsI[IOFF_CU1 + s], 1);
    wsI[IOFF_PLIST + pos] = i;
  } else if (i < NPIX + M1C) {
    int r = i - NPIX;
    int pos = atomicAdd(&wsI[IOFF_CUC2 + c2[r]], 1);
    wsI[IOFF_R2L + pos] = r;
  } else if (i < NPIX + M1C + E1C) {
    int e = i - NPIX - M1C;
    int pos = atomicAdd(&wsI[IOFF_CUE1 + e1[E1C + e]], 1);
    wsI[IOFF_E1L + pos] = e1[e];
  } else {
    int e = i - NPIX - M1C - E1C;
    int pos = atomicAdd(&wsI[IOFF_CUE2 + e2[E2C + e]], 1);
    wsI[IOFF_E2L + pos] = e2[e];
  }
}

// ---------------- block-level dense layer (coalesced W loads; RPT-row amortization) ----------------
template<int NIN, int NOUT, int R, bool RELU>
__device__ __forceinline__ void block_layer(
    const float* __restrict__ W, const float* __restrict__ B,
    const float* __restrict__ actIn, float* __restrict__ actOut, int tid) {
  constexpr int NG  = 256 / NOUT;
  constexpr int RPT = (R + NG - 1) / NG;
  static_assert(NIN % 4 == 0, "NIN must be multiple of 4");
  int c  = tid % NOUT;
  int rg = tid / NOUT;
  if (rg < NG) {
    float acc[RPT];
    #pragma unroll
    for (int i = 0; i < RPT; ++i) acc[i] = 0.f;
    #pragma unroll 4
    for (int kc = 0; kc < NIN/4; ++kc) {
      float w0 = W[(kc*4+0)*NOUT + c];
      float w1 = W[(kc*4+1)*NOUT + c];
      float w2 = W[(kc*4+2)*NOUT + c];
      float w3 = W[(kc*4+3)*NOUT + c];
      #pragma unroll
      for (int i = 0; i < RPT; ++i) {
        int r = rg + i*NG;
        if (r < R) {
          float4 a = *reinterpret_cast<const float4*>(actIn + r*NIN + kc*4);
          acc[i] = fmaf(a.x, w0, fmaf(a.y, w1, fmaf(a.z, w2, fmaf(a.w, w3, acc[i]))));
        }
      }
    }
    float b = B[c];
    #pragma unroll
    for (int i = 0; i < RPT; ++i) {
      int r = rg + i*NG;
      if (r < R) {
        float v = acc[i] + b;
        actOut[r*NOUT + c] = RELU ? fmaxf(v, 0.f) : v;
      }
    }
  }
  __syncthreads();
}

// ==================== K1: padded-img gather + t1 MLP (8 clusters/block, 2/wave) ====================
__global__ __launch_bounds__(256) void k1_gather_t1(
    const float* __restrict__ pad, const float* __restrict__ cw, const float* __restrict__ cb,
    const int* __restrict__ start, const int* __restrict__ plist,
    const float* t1_wi, const float* t1_bi, const float* t1_wh, const float* t1_bh,
    const float* t1_wo, const float* t1_bo,
    float* __restrict__ x1fc, float* __restrict__ s1c_raw, float* __restrict__ c1f,
    float* __restrict__ jsf1) {
  int tid = threadIdx.x, wv = tid >> 6, l = tid & 63;
  __shared__ __align__(16) float bufA[8*100];
  __shared__ __align__(16) float bufB[8*100];
  // --- gather phase: each wave handles 2 consecutive clusters ---
  #pragma unroll
  for (int cc = 0; cc < 2; ++cc) {
    int row = wv*2 + cc;
    int s = blockIdx.x*8 + row;
    int p0 = start[s], p1 = start[s+1];
    int count = p1 - p0;
    float ps[27];
    #pragma unroll
    for (int k = 0; k < 27; ++k) ps[k] = 0.f;
    float sy = 0.f, sx = 0.f, syy = 0.f, sxx = 0.f;
    for (int p = p0 + l; p < p1; p += 64) {
      int n = plist[p];
      int b = n >> 16, pp = n & 65535, i = pp >> 8, j = pp & 255;
      const float* pb = pad + (size_t)b*PAD_BATCH + i*PAD_ROW + j*3;
      #pragma unroll
      for (int di = 0; di < 3; ++di) {
        const float* rp = pb + di*PAD_ROW;
        #pragma unroll
        for (int t = 0; t < 9; ++t) ps[di*9 + t] += rp[t];
      }
      float yi = i * (1.0f/256.0f), xj = j * (1.0f/256.0f);
      sy += yi; sx += xj; syy += yi*yi; sxx += xj*xj;
    }
    #pragma unroll
    for (int m = 1; m < 64; m <<= 1) {
      #pragma unroll
      for (int k = 0; k < 27; ++k) ps[k] += __shfl_xor(ps[k], m);
      sy  += __shfl_xor(sy,  m);
      sx  += __shfl_xor(sx,  m);
      syy += __shfl_xor(syy, m);
      sxx += __shfl_xor(sxx, m);
    }
    float inv = 1.0f / fmaxf((float)count, 1.0f);
    float o = cb[l];
    #pragma unroll
    for (int k = 0; k < 27; ++k) o = fmaf(ps[k]*inv, cw[k*64 + l], o);
    bufA[row*68 + l] = count ? o : 0.f;             // x1cat row lives in LDS only
    if (l == 0) {
      bufA[row*68 + 64] = sy*inv;
      bufA[row*68 + 65] = sx*inv;
      bufA[row*68 + 66] = syy*inv;
      bufA[row*68 + 67] = sxx*inv;
      s1c_raw[s*4+0] = sy; s1c_raw[s*4+1] = sx;
      s1c_raw[s*4+2] = syy; s1c_raw[s*4+3] = sxx;
      jsf1[s*20 + 18] = sy*inv;
      jsf1[s*20 + 19] = sx*inv;
      c1f[s] = (float)count;
    }
  }
  __syncthreads();
  // --- t1 MLP on the block's 8 rows ---
  block_layer<68,100,8,true>(t1_wi, t1_bi, bufA, bufB, tid);
  block_layer<100,100,8,true>(t1_wh, t1_bh, bufB, bufA, tid);
  block_layer<100,100,8,true>(t1_wh+10000, t1_bh+100, bufA, bufB, tid);
  block_layer<100,64,8,false>(t1_wo, t1_bo, bufB, bufA, tid);
  int r0 = blockIdx.x*8;
  for (int o2 = tid; o2 < 8*64; o2 += 256) x1fc[r0*64 + o2] = bufA[o2];
}

// ---------------- edge mean with 4-wide pipelined accumulation ----------------
__device__ __forceinline__ float edge_mean(
    const int* __restrict__ elist, const float* __restrict__ xin,
    int p0, int p1, int l) {
  float a0 = 0.f, a1 = 0.f, a2 = 0.f, a3 = 0.f;
  int p = p0;
  for (; p + 3 < p1; p += 4) {
    int s0 = elist[p], s1 = elist[p+1], s2 = elist[p+2], s3 = elist[p+3];
    a0 += xin[s0*64 + l];
    a1 += xin[s1*64 + l];
    a2 += xin[s2*64 + l];
    a3 += xin[s3*64 + l];
  }
  for (; p < p1; ++p) a0 += xin[elist[p]*64 + l];
  return ((a0 + a1) + (a2 + a3)) / fmaxf((float)(p1 - p0), 1.0f);
}

// ==================== K2: gc1 + q-MLP(x1) (8 dst/block, 2/wave, 512 blocks) ====================
__global__ __launch_bounds__(256) void k2_gc1_q(
    const int* __restrict__ startE, const int* __restrict__ elist,
    const float* __restrict__ xin,
    const float* wn, const float* wsf, const float* bias,
    const float* q_wi, const float* q_bi, const float* q_wh, const float* q_bh,
    const float* q_wo, const float* q_bo,
    float* __restrict__ x1_ws, float* __restrict__ out_f, float* __restrict__ jsf) {
  int tid = threadIdx.x, wv = tid >> 6, l = tid & 63;
  __shared__ __align__(16) float bufA[8*100];
  __shared__ __align__(16) float bufB[8*100];
  __shared__ float smW[4*128];
  float* sm = smW + wv*128;                      // wave-private region
  #pragma unroll
  for (int cc = 0; cc < 2; ++cc) {
    int row = wv*2 + cc;
    int d = blockIdx.x*8 + row;
    // graph conv (wave-local LDS: no block barrier needed between fill and use)
    sm[l]      = edge_mean(elist, xin, startE[d], startE[d+1], l);
    sm[64 + l] = xin[d*64 + l];
    float o = bias[l];
    #pragma unroll 8
    for (int k = 0; k < 64; ++k)
      o += sm[k]*wn[k*64 + l] + sm[64 + k]*wsf[k*64 + l];
    x1_ws[d*64 + l] = o;
    out_f[d*64 + l] = o;
    bufA[row*64 + l] = o;
  }
  __syncthreads();
  // --- q MLP on the 8 fresh rows ---
  block_layer<64,100,8,true>(q_wi, q_bi, bufA, bufB, tid);
  block_layer<100,100,8,true>(q_wh, q_bh, bufB, bufA, tid);
  block_layer<100,100,8,true>(q_wh+10000, q_bh+100, bufA, bufB, tid);
  block_layer<100,18,8,false>(q_wo, q_bo, bufB, bufA, tid);
  int r0 = blockIdx.x*8;
  for (int o2 = tid; o2 < 8*18; o2 += 256) {
    int r = o2 / 18, c = o2 - r*18;
    jsf[(r0+r)*20 + c] = bufA[o2];
  }
}

// ==================== K3: pool_l2 + t2 MLP (4 clusters/block, 128 blocks) ====================
__global__ __launch_bounds__(256) void k3_pool_t2(
    const int* __restrict__ startc2, const int* __restrict__ r2list,
    const float* __restrict__ x1, const float* __restrict__ s1c_raw, const float* __restrict__ c1f,
    const float* t2_wi, const float* t2_bi, const float* t2_wh, const float* t2_bh,
    const float* t2_wo, const float* t2_bo,
    float* __restrict__ x2fc, float* __restrict__ jsf2) {
  int tid = threadIdx.x, wv = tid >> 6, l = tid & 63;
  int s2 = blockIdx.x*4 + wv;
  __shared__ __align__(16) float bufA[4*100];
  __shared__ __align__(16) float bufB[4*100];
  int p0 = startc2[s2], p1 = startc2[s2+1];
  int k = l & 3;
  float acc = 0.f, sc = 0.f, cnt = 0.f;
  for (int p = p0; p < p1; ++p) {
    int r = r2list[p];
    acc += x1[r*64 + l];
    sc  += s1c_raw[r*4 + k];
    cnt += c1f[r];
  }
  float invr = 1.0f / fmaxf((float)(p1 - p0), 1.0f);
  bufA[wv*68 + l] = acc * invr;
  if (l < 4) {
    float mean = sc / fmaxf(cnt, 1.0f);
    bufA[wv*68 + 64 + l] = mean;
    if (l == 0) jsf2[s2*20 + 18] = mean;
    if (l == 1) jsf2[s2*20 + 19] = mean;
  }
  __syncthreads();
  block_layer<68,100,4,true>(t2_wi, t2_bi, bufA, bufB, tid);
  block_layer<100,100,4,true>(t2_wh, t2_bh, bufB, bufA, tid);
  block_layer<100,100,4,true>(t2_wh+10000, t2_bh+100, bufA, bufB, tid);
  block_layer<100,64,4,false>(t2_wo, t2_bo, bufB, bufA, tid);
  int r0 = blockIdx.x*4;
  for (int o2 = tid; o2 < 4*64; o2 += 256) x2fc[r0*64 + o2] = bufA[o2];
}

// ==================== K4: gc2 + q-MLP(x2) (4 rows/block, 128 blocks) ====================
__global__ __launch_bounds__(256) void k4_gc2_q(
    const int* __restrict__ startE, const int* __restrict__ elist,
    const float* __restrict__ xin,
    const float* wn, const float* wsf, const float* bias,
    const float* q_wi, const float* q_bi, const float* q_wh, const float* q_bh,
    const float* q_wo, const float* q_bo,
    float* __restrict__ out_f, float* __restrict__ jsf2) {
  int tid = threadIdx.x, wv = tid >> 6, l = tid & 63;
  int d = blockIdx.x*4 + wv;
  __shared__ __align__(16) float bufA[4*100];
  __shared__ __align__(16) float bufB[4*100];
  __shared__ float smW[4*128];
  float* sm = smW + wv*128;
  sm[l]      = edge_mean(elist, xin, startE[d], startE[d+1], l);
  sm[64 + l] = xin[d*64 + l];
  __syncthreads();
  float o = bias[l];
  #pragma unroll 8
  for (int k = 0; k < 64; ++k)
    o += sm[k]*wn[k*64 + l] + sm[64 + k]*wsf[k*64 + l];
  out_f[d*64 + l] = o;
  bufA[wv*64 + l] = o;
  __syncthreads();
  block_layer<64,100,4,true>(q_wi, q_bi, bufA, bufB, tid);
  block_layer<100,100,4,true>(q_wh, q_bh, bufB, bufA, tid);
  block_layer<100,100,4,true>(q_wh+10000, q_bh+100, bufA, bufB, tid);
  block_layer<100,18,4,false>(q_wo, q_bo, bufB, bufA, tid);
  int r0 = blockIdx.x*4;
  for (int o2 = tid; o2 < 4*18; o2 += 256) {
    int r = o2 / 18, c = o2 - r*18;
    jsf2[(r0+r)*20 + c] = bufA[o2];
  }
}

// ---------------- quadratic render (float4 jsf reads) ----------------
__global__ __launch_bounds__(256) void render_kernel(
    const int* __restrict__ cluster1, const int* __restrict__ cluster2,
    const float* __restrict__ jsf1, const float* __restrict__ jsf2,
    float* __restrict__ r1, float* __restrict__ r2) {
  int n = blockIdx.x*256 + threadIdx.x;
  int p = n & 65535, i = p >> 8, j = p & 255;
  float gy = i * (1.0f/256.0f), gx = j * (1.0f/256.0f);
  int s = cluster1[n];
  {
    const float4* f4 = reinterpret_cast<const float4*>(jsf1 + s*20);
    float4 v0 = f4[0], v1 = f4[1], v2 = f4[2], v3 = f4[3], v4 = f4[4];
    float dx = gy - v0.x, dy = gx - v0.y;
    float dxx = dx*dx, dyy = dy*dy, dxy = dx*dy;
    r1[n*3 + 0] = v0.z + v0.w*dx + v1.x*dy + v1.y*dxx + v1.z*dyy + v1.w*dxy;
    r1[n*3 + 1] = v2.x + v2.y*dx + v2.z*dy + v2.w*dxx + v3.x*dyy + v3.y*dxy;
    r1[n*3 + 2] = v3.z + v3.w*dx + v4.x*dy + v4.y*dxx + v4.z*dyy + v4.w*dxy;
  }
  int s2 = cluster2[s];
  {
    const float4* f4 = reinterpret_cast<const float4*>(jsf2 + s2*20);
    float4 v0 = f4[0], v1 = f4[1], v2 = f4[2], v3 = f4[3], v4 = f4[4];
    float dx = gy - v0.x, dy = gx - v0.y;
    float dxx = dx*dx, dyy = dy*dy, dxy = dx*dy;
    r2[n*3 + 0] = v0.z + v0.w*dx + v1.x*dy + v1.y*dxx + v1.z*dyy + v1.w*dxy;
    r2[n*3 + 1] = v2.x + v2.y*dx + v2.z*dy + v2.w*dxx + v3.x*dyy + v3.y*dxy;
    r2[n*3 + 2] = v3.z + v3.w*dx + v4.x*dy + v4.y*dxx + v4.z*dyy + v4.w*dxy;
  }
}

extern "C" void kernel_launch(void* const* d_in, const int* in_sizes, int n_in,
                              void* d_out, int out_size, void* d_ws, size_t ws_size,
                              hipStream_t stream) {
  const float* img    = (const float*)d_in[0];
  const float* conv_w = (const float*)d_in[1];
  const float* conv_b = (const float*)d_in[2];
  const float* t1_wi = (const float*)d_in[3];  const float* t1_bi = (const float*)d_in[4];
  const float* t1_wh = (const float*)d_in[5];  const float* t1_bh = (const float*)d_in[6];
  const float* t1_wo = (const float*)d_in[7];  const float* t1_bo = (const float*)d_in[8];
  const float* t2_wi = (const float*)d_in[9];  const float* t2_bi = (const float*)d_in[10];
  const float* t2_wh = (const float*)d_in[11]; const float* t2_bh = (const float*)d_in[12];
  const float* t2_wo = (const float*)d_in[13]; const float* t2_bo = (const float*)d_in[14];
  const float* q_wi  = (const float*)d_in[15]; const float* q_bi  = (const float*)d_in[16];
  const float* q_wh  = (const float*)d_in[17]; const float* q_bh  = (const float*)d_in[18];
  const float* q_wo  = (const float*)d_in[19]; const float* q_bo  = (const float*)d_in[20];
  const float* gc1_wn = (const float*)d_in[21]; const float* gc1_ws = (const float*)d_in[22];
  const float* gc1_b  = (const float*)d_in[23];
  const float* gc2_wn = (const float*)d_in[24]; const float* gc2_ws = (const float*)d_in[25];
  const float* gc2_b  = (const float*)d_in[26];
  const int* cluster1 = (const int*)d_in[27];
  const int* cluster2 = (const int*)d_in[28];
  const int* edges1   = (const int*)d_in[29];
  const int* edges2   = (const int*)d_in[30];

  float* ws = (float*)d_ws;
  int*   wsI = (int*)d_ws;
  float* out  = (float*)d_out;
  float* o_r1 = out;
  float* o_r2 = out + 786432;
  float* o_x1 = out + 1572864;
  float* o_x2 = out + 1835008;

  // prep: zero histograms + padded image (one launch)
  prep<<<(PAD_TOT + 255)/256, 256, 0, stream>>>(img, ws + OFF_PAD, wsI);

  constexpr int TOTW = NPIX + M1C + E1C + E2C;   // 339968, /256 = 1328 exact
  build_hist<<<TOTW/256, 256, 0, stream>>>(cluster1, cluster2, edges1, edges2, wsI);
  scan_kernel<<<4, 1024, 0, stream>>>(wsI);
  scatter_all<<<TOTW/256, 256, 0, stream>>>(cluster1, cluster2, edges1, edges2, wsI);

  // K1: padded-img gather + t1 MLP (8 clusters/block, 512 blocks)
  k1_gather_t1<<<M1C/8, 256, 0, stream>>>(ws + OFF_PAD, conv_w, conv_b,
      wsI+IOFF_ST1, wsI+IOFF_PLIST,
      t1_wi, t1_bi, t1_wh, t1_bh, t1_wo, t1_bo,
      ws+OFF_X1FC, ws+OFF_S1CR, ws+OFF_C1, ws+OFF_JSF1);

  // K2: graph conv 1 + q MLP on x1 rows (8 dst/block, 512 blocks)
  k2_gc1_q<<<M1C/8, 256, 0, stream>>>(wsI+IOFF_STE1, wsI+IOFF_E1L, ws+OFF_X1FC,
      gc1_wn, gc1_ws, gc1_b,
      q_wi, q_bi, q_wh, q_bh, q_wo, q_bo,
      ws+OFF_X1, o_x1, ws+OFF_JSF1);

  // K3: level-2 pooling + t2 MLP
  k3_pool_t2<<<M2C/4, 256, 0, stream>>>(wsI+IOFF_STC2, wsI+IOFF_R2L,
      ws+OFF_X1, ws+OFF_S1CR, ws+OFF_C1,
      t2_wi, t2_bi, t2_wh, t2_bh, t2_wo, t2_bo,
      ws+OFF_X2FC, ws+OFF_JSF2);

  // K4: graph conv 2 + q MLP on x2 rows
  k4_gc2_q<<<M2C/4, 256, 0, stream>>>(wsI+IOFF_STE2, wsI+IOFF_E2L, ws+OFF_X2FC,
      gc2_wn, gc2_ws, gc2_b,
      q_wi, q_bi, q_wh, q_bh, q_wo, q_bo,
      o_x2, ws+OFF_JSF2);

  // render
  render_kernel<<<NPIX/256, 256, 0, stream>>>(cluster1, cluster2, ws+OFF_JSF1, ws+OFF_JSF2, o_r1, o_r2);
}

// Round 15
// 165.390 us; speedup vs baseline: 1.2377x; 1.0154x over previous
//
#include <hip/hip_runtime.h>

#define NPIX 262144   // B*H*H = 4*256*256
#define M1C 4096
#define M2C 512
#define E1C 65536
#define E2C 8192

// ---- workspace layout (4-byte element offsets) ----
// zeroed region (int histograms only):
constexpr int IOFF_H1   = 0;                 // 4096
constexpr int IOFF_HC2  = IOFF_H1  + M1C;    // 512
constexpr int IOFF_HE1  = IOFF_HC2 + M2C;    // 4096
constexpr int IOFF_HE2  = IOFF_HE1 + M1C;    // 512
constexpr int ZEROI_END = IOFF_HE2 + M2C;    // 9216 ints

constexpr int IOFF_ST1   = ZEROI_END;              // 4097
constexpr int IOFF_CU1   = IOFF_ST1  + M1C + 1;    // 4096
constexpr int IOFF_STC2  = IOFF_CU1  + M1C;        // 513
constexpr int IOFF_CUC2  = IOFF_STC2 + M2C + 1;    // 512
constexpr int IOFF_STE1  = IOFF_CUC2 + M2C;        // 4097
constexpr int IOFF_CUE1  = IOFF_STE1 + M1C + 1;    // 4096
constexpr int IOFF_STE2  = IOFF_CUE1 + M1C;        // 513
constexpr int IOFF_CUE2  = IOFF_STE2 + M2C + 1;    // 512
constexpr int IOFF_PLIST = IOFF_CUE2 + M2C;        // 262144 (pixels sorted by cluster)
constexpr int IOFF_R2L   = IOFF_PLIST + NPIX;      // 4096
constexpr int IOFF_E1L   = IOFF_R2L + M1C;         // 65536
constexpr int IOFF_E2L   = IOFF_E1L + E1C;         // 8192
constexpr int IEND0      = IOFF_E2L + E2C;
constexpr int IEND       = (IEND0 + 3) & ~3;       // 16B-align float region

// float scratch:
constexpr int OFF_S1CR  = IEND;                    // 4096*4 raw coord sums
constexpr int OFF_C1    = OFF_S1CR + M1C*4;        // 4096 counts
constexpr int OFF_X1FC  = OFF_C1 + M1C;            // 4096*64 (t1 out, gc1 in)
constexpr int OFF_X1    = OFF_X1FC + M1C*64;       // 4096*64 (gc1 out, pool in)
constexpr int OFF_X2FC  = OFF_X1 + M1C*64;         // 512*64  (t2 out, gc2 in)
constexpr int OFF_JSF1  = OFF_X2FC + M2C*64;       // 4096*20 (80B rows, 16B-aligned)
constexpr int OFF_JSF2  = OFF_JSF1 + M1C*20;       // 512*20
constexpr int OFF_PAD   = OFF_JSF2 + M2C*20;       // 4*258*258*3 zero-padded img

#define PAD_ROW   774        // 258*3
#define PAD_BATCH 199692     // 258*774
#define PAD_TOT   266256     // 4*258*258

// ---------------- prep: zero histograms + build zero-padded image (one launch) ----------------
__global__ __launch_bounds__(256) void prep(
    const float* __restrict__ img, float* __restrict__ pad, int* __restrict__ wsI) {
  int idx = blockIdx.x*256 + threadIdx.x;
  if (idx < ZEROI_END) wsI[idx] = 0;
  if (idx >= PAD_TOT) return;
  int b = idx / 66564, r = idx - b*66564;
  int py = r / 258, px = r - py*258;
  float v0 = 0.f, v1 = 0.f, v2 = 0.f;
  int y = py - 1, x = px - 1;
  if ((unsigned)y < 256u && (unsigned)x < 256u) {
    const float* s = img + (size_t)(((b << 16) + (y << 8) + x) * 3);
    v0 = s[0]; v1 = s[1]; v2 = s[2];
  }
  float* d = pad + (size_t)idx*3;
  d[0] = v0; d[1] = v1; d[2] = v2;
}

// ---------------- fused histograms ----------------
__global__ __launch_bounds__(256) void build_hist(
    const int* __restrict__ c1, const int* __restrict__ c2,
    const int* __restrict__ e1, const int* __restrict__ e2, int* __restrict__ wsI) {
  int i = blockIdx.x*256 + threadIdx.x;
  if (i < NPIX) {
    atomicAdd(&wsI[IOFF_H1 + c1[i]], 1);
  } else if (i < NPIX + M1C) {
    atomicAdd(&wsI[IOFF_HC2 + c2[i - NPIX]], 1);
  } else if (i < NPIX + M1C + E1C) {
    int e = i - NPIX - M1C;
    atomicAdd(&wsI[IOFF_HE1 + e1[E1C + e]], 1);
  } else {
    int e = i - NPIX - M1C - E1C;
    atomicAdd(&wsI[IOFF_HE2 + e2[E2C + e]], 1);
  }
}

// ---------------- exclusive scan, one block per histogram ----------------
__global__ __launch_bounds__(1024) void scan_kernel(int* __restrict__ wsI) {
  const int* hist; int* start; int* curs; int n;
  if (blockIdx.x == 0)      { hist = wsI+IOFF_H1;  start = wsI+IOFF_ST1;  curs = wsI+IOFF_CU1;  n = M1C; }
  else if (blockIdx.x == 1) { hist = wsI+IOFF_HC2; start = wsI+IOFF_STC2; curs = wsI+IOFF_CUC2; n = M2C; }
  else if (blockIdx.x == 2) { hist = wsI+IOFF_HE1; start = wsI+IOFF_STE1; curs = wsI+IOFF_CUE1; n = M1C; }
  else                      { hist = wsI+IOFF_HE2; start = wsI+IOFF_STE2; curs = wsI+IOFF_CUE2; n = M2C; }
  __shared__ int part[1024];
  int t = threadIdx.x, base = t*4, sum = 0;
  int loc0, loc1, loc2, loc3;
  loc0 = sum; sum += (base+0 < n) ? hist[base+0] : 0;
  loc1 = sum; sum += (base+1 < n) ? hist[base+1] : 0;
  loc2 = sum; sum += (base+2 < n) ? hist[base+2] : 0;
  loc3 = sum; sum += (base+3 < n) ? hist[base+3] : 0;
  part[t] = sum;
  __syncthreads();
  for (int off = 1; off < 1024; off <<= 1) {
    int v = (t >= off) ? part[t-off] : 0;
    __syncthreads();
    part[t] += v;
    __syncthreads();
  }
  int excl = (t == 0) ? 0 : part[t-1];
  if (base+0 < n) { start[base+0] = excl+loc0; curs[base+0] = excl+loc0; }
  if (base+1 < n) { start[base+1] = excl+loc1; curs[base+1] = excl+loc1; }
  if (base+2 < n) { start[base+2] = excl+loc2; curs[base+2] = excl+loc2; }
  if (base+3 < n) { start[base+3] = excl+loc3; curs[base+3] = excl+loc3; }
  if (t == 0) start[n] = part[1023];
}

// ---------------- fused scatter into bins ----------------
__global__ __launch_bounds__(256) void scatter_all(
    const int* __restrict__ c1, const int* __restrict__ c2,
    const int* __restrict__ e1, const int* __restrict__ e2, int* __restrict__ wsI) {
  int i = blockIdx.x*256 + threadIdx.x;
  if (i < NPIX) {
    int s = c1[i];
    int pos = atomicAdd(&wsI[IOFF_CU1 + s], 1);
    wsI[IOFF_PLIST + pos] = i;
  } else if (i < NPIX + M1C) {
    int r = i - NPIX;
    int pos = atomicAdd(&wsI[IOFF_CUC2 + c2[r]], 1);
    wsI[IOFF_R2L + pos] = r;
  } else if (i < NPIX + M1C + E1C) {
    int e = i - NPIX - M1C;
    int pos = atomicAdd(&wsI[IOFF_CUE1 + e1[E1C + e]], 1);
    wsI[IOFF_E1L + pos] = e1[e];
  } else {
    int e = i - NPIX - M1C - E1C;
    int pos = atomicAdd(&wsI[IOFF_CUE2 + e2[E2C + e]], 1);
    wsI[IOFF_E2L + pos] = e2[e];
  }
}

// ---------------- block-level dense layer (coalesced W loads; RPT-row amortization) ----------------
template<int NIN, int NOUT, int R, bool RELU>
__device__ __forceinline__ void block_layer(
    const float* __restrict__ W, const float* __restrict__ B,
    const float* __restrict__ actIn, float* __restrict__ actOut, int tid) {
  constexpr int NG  = 256 / NOUT;
  constexpr int RPT = (R + NG - 1) / NG;
  static_assert(NIN % 4 == 0, "NIN must be multiple of 4");
  int c  = tid % NOUT;
  int rg = tid / NOUT;
  if (rg < NG) {
    float acc[RPT];
    #pragma unroll
    for (int i = 0; i < RPT; ++i) acc[i] = 0.f;
    #pragma unroll 4
    for (int kc = 0; kc < NIN/4; ++kc) {
      float w0 = W[(kc*4+0)*NOUT + c];
      float w1 = W[(kc*4+1)*NOUT + c];
      float w2 = W[(kc*4+2)*NOUT + c];
      float w3 = W[(kc*4+3)*NOUT + c];
      #pragma unroll
      for (int i = 0; i < RPT; ++i) {
        int r = rg + i*NG;
        if (r < R) {
          float4 a = *reinterpret_cast<const float4*>(actIn + r*NIN + kc*4);
          acc[i] = fmaf(a.x, w0, fmaf(a.y, w1, fmaf(a.z, w2, fmaf(a.w, w3, acc[i]))));
        }
      }
    }
    float b = B[c];
    #pragma unroll
    for (int i = 0; i < RPT; ++i) {
      int r = rg + i*NG;
      if (r < R) {
        float v = acc[i] + b;
        actOut[r*NOUT + c] = RELU ? fmaxf(v, 0.f) : v;
      }
    }
  }
  __syncthreads();
}

// ==================== K1: padded-img gather + t1 MLP (8 clusters/block, 2/wave) ====================
// Reduction: register-halving butterfly (31 bpermutes) instead of all-reduce (186).
__global__ __launch_bounds__(256) void k1_gather_t1(
    const float* __restrict__ pad, const float* __restrict__ cw, const float* __restrict__ cb,
    const int* __restrict__ start, const int* __restrict__ plist,
    const float* t1_wi, const float* t1_bi, const float* t1_wh, const float* t1_bh,
    const float* t1_wo, const float* t1_bo,
    float* __restrict__ x1fc, float* __restrict__ s1c_raw, float* __restrict__ c1f,
    float* __restrict__ jsf1) {
  int tid = threadIdx.x, wv = tid >> 6, l = tid & 63;
  __shared__ __align__(16) float bufA[8*100];
  __shared__ __align__(16) float bufB[8*100];
  // --- gather phase: each wave handles 2 consecutive clusters ---
  #pragma unroll
  for (int cc = 0; cc < 2; ++cc) {
    int row = wv*2 + cc;
    int s = blockIdx.x*8 + row;
    int p0 = start[s], p1 = start[s+1];
    int count = p1 - p0;
    float v[32];
    #pragma unroll
    for (int k = 0; k < 32; ++k) v[k] = 0.f;
    for (int p = p0 + l; p < p1; p += 64) {
      int n = plist[p];
      int b = n >> 16, pp = n & 65535, i = pp >> 8, j = pp & 255;
      const float* pb = pad + (size_t)b*PAD_BATCH + i*PAD_ROW + j*3;
      #pragma unroll
      for (int di = 0; di < 3; ++di) {
        const float* rp = pb + di*PAD_ROW;
        #pragma unroll
        for (int t = 0; t < 9; ++t) v[di*9 + t] += rp[t];
      }
      float yi = i * (1.0f/256.0f), xj = j * (1.0f/256.0f);
      v[27] += yi; v[28] += xj; v[29] += yi*yi; v[30] += xj*xj;
    }
    // register-halving butterfly: after 5 steps lane l holds half-sum of value (l&31)
    #pragma unroll
    for (int j = 0; j < 16; ++j) {
      float a0 = v[2*j], a1 = v[2*j+1];
      float send = (l & 1) ? a0 : a1;
      float recv = __shfl_xor(send, 1);
      v[j] = ((l & 1) ? a1 : a0) + recv;
    }
    #pragma unroll
    for (int j = 0; j < 8; ++j) {
      float a0 = v[2*j], a1 = v[2*j+1];
      float send = (l & 2) ? a0 : a1;
      float recv = __shfl_xor(send, 2);
      v[j] = ((l & 2) ? a1 : a0) + recv;
    }
    #pragma unroll
    for (int j = 0; j < 4; ++j) {
      float a0 = v[2*j], a1 = v[2*j+1];
      float send = (l & 4) ? a0 : a1;
      float recv = __shfl_xor(send, 4);
      v[j] = ((l & 4) ? a1 : a0) + recv;
    }
    #pragma unroll
    for (int j = 0; j < 2; ++j) {
      float a0 = v[2*j], a1 = v[2*j+1];
      float send = (l & 8) ? a0 : a1;
      float recv = __shfl_xor(send, 8);
      v[j] = ((l & 8) ? a1 : a0) + recv;
    }
    {
      float a0 = v[0], a1 = v[1];
      float send = (l & 16) ? a0 : a1;
      float recv = __shfl_xor(send, 16);
      v[0] = ((l & 16) ? a1 : a0) + recv;
    }
    float tot = v[0] + __shfl_xor(v[0], 32);     // full sum of value (l&31)
    float inv = 1.0f / fmaxf((float)count, 1.0f);
    // conv: lane c consumes broadcasts of the 27 patch totals (v_readlane, scalar)
    float o = cb[l];
    #pragma unroll
    for (int k = 0; k < 27; ++k) o = fmaf(__shfl(tot, k)*inv, cw[k*64 + l], o);
    bufA[row*68 + l] = count ? o : 0.f;           // x1cat row lives in LDS only
    float syt = __shfl(tot, 27), sxt = __shfl(tot, 28);
    float syyt = __shfl(tot, 29), sxxt = __shfl(tot, 30);
    if (l == 0) {
      bufA[row*68 + 64] = syt*inv;
      bufA[row*68 + 65] = sxt*inv;
      bufA[row*68 + 66] = syyt*inv;
      bufA[row*68 + 67] = sxxt*inv;
      s1c_raw[s*4+0] = syt; s1c_raw[s*4+1] = sxt;
      s1c_raw[s*4+2] = syyt; s1c_raw[s*4+3] = sxxt;
      jsf1[s*20 + 18] = syt*inv;
      jsf1[s*20 + 19] = sxt*inv;
      c1f[s] = (float)count;
    }
  }
  __syncthreads();
  // --- t1 MLP on the block's 8 rows ---
  block_layer<68,100,8,true>(t1_wi, t1_bi, bufA, bufB, tid);
  block_layer<100,100,8,true>(t1_wh, t1_bh, bufB, bufA, tid);
  block_layer<100,100,8,true>(t1_wh+10000, t1_bh+100, bufA, bufB, tid);
  block_layer<100,64,8,false>(t1_wo, t1_bo, bufB, bufA, tid);
  int r0 = blockIdx.x*8;
  for (int o2 = tid; o2 < 8*64; o2 += 256) x1fc[r0*64 + o2] = bufA[o2];
}

// ---------------- edge mean with 4-wide pipelined accumulation ----------------
__device__ __forceinline__ float edge_mean(
    const int* __restrict__ elist, const float* __restrict__ xin,
    int p0, int p1, int l) {
  float a0 = 0.f, a1 = 0.f, a2 = 0.f, a3 = 0.f;
  int p = p0;
  for (; p + 3 < p1; p += 4) {
    int s0 = elist[p], s1 = elist[p+1], s2 = elist[p+2], s3 = elist[p+3];
    a0 += xin[s0*64 + l];
    a1 += xin[s1*64 + l];
    a2 += xin[s2*64 + l];
    a3 += xin[s3*64 + l];
  }
  for (; p < p1; ++p) a0 += xin[elist[p]*64 + l];
  return ((a0 + a1) + (a2 + a3)) / fmaxf((float)(p1 - p0), 1.0f);
}

// ==================== K2: gc1 + q-MLP(x1) (8 dst/block, 2/wave, 512 blocks) ====================
__global__ __launch_bounds__(256) void k2_gc1_q(
    const int* __restrict__ startE, const int* __restrict__ elist,
    const float* __restrict__ xin,
    const float* wn, const float* wsf, const float* bias,
    const float* q_wi, const float* q_bi, const float* q_wh, const float* q_bh,
    const float* q_wo, const float* q_bo,
    float* __restrict__ x1_ws, float* __restrict__ out_f, float* __restrict__ jsf) {
  int tid = threadIdx.x, wv = tid >> 6, l = tid & 63;
  __shared__ __align__(16) float bufA[8*100];
  __shared__ __align__(16) float bufB[8*100];
  __shared__ float smW[4*128];
  float* sm = smW + wv*128;                      // wave-private region
  #pragma unroll
  for (int cc = 0; cc < 2; ++cc) {
    int row = wv*2 + cc;
    int d = blockIdx.x*8 + row;
    sm[l]      = edge_mean(elist, xin, startE[d], startE[d+1], l);
    sm[64 + l] = xin[d*64 + l];
    float o = bias[l];
    #pragma unroll 8
    for (int k = 0; k < 64; ++k)
      o += sm[k]*wn[k*64 + l] + sm[64 + k]*wsf[k*64 + l];
    x1_ws[d*64 + l] = o;
    out_f[d*64 + l] = o;
    bufA[row*64 + l] = o;
  }
  __syncthreads();
  // --- q MLP on the 8 fresh rows ---
  block_layer<64,100,8,true>(q_wi, q_bi, bufA, bufB, tid);
  block_layer<100,100,8,true>(q_wh, q_bh, bufB, bufA, tid);
  block_layer<100,100,8,true>(q_wh+10000, q_bh+100, bufA, bufB, tid);
  block_layer<100,18,8,false>(q_wo, q_bo, bufB, bufA, tid);
  int r0 = blockIdx.x*8;
  for (int o2 = tid; o2 < 8*18; o2 += 256) {
    int r = o2 / 18, c = o2 - r*18;
    jsf[(r0+r)*20 + c] = bufA[o2];
  }
}

// ==================== K3: pool_l2 + t2 MLP (4 clusters/block, 128 blocks) ====================
__global__ __launch_bounds__(256) void k3_pool_t2(
    const int* __restrict__ startc2, const int* __restrict__ r2list,
    const float* __restrict__ x1, const float* __restrict__ s1c_raw, const float* __restrict__ c1f,
    const float* t2_wi, const float* t2_bi, const float* t2_wh, const float* t2_bh,
    const float* t2_wo, const float* t2_bo,
    float* __restrict__ x2fc, float* __restrict__ jsf2) {
  int tid = threadIdx.x, wv = tid >> 6, l = tid & 63;
  int s2 = blockIdx.x*4 + wv;
  __shared__ __align__(16) float bufA[4*100];
  __shared__ __align__(16) float bufB[4*100];
  int p0 = startc2[s2], p1 = startc2[s2+1];
  int k = l & 3;
  float acc = 0.f, sc = 0.f, cnt = 0.f;
  for (int p = p0; p < p1; ++p) {
    int r = r2list[p];
    acc += x1[r*64 + l];
    sc  += s1c_raw[r*4 + k];
    cnt += c1f[r];
  }
  float invr = 1.0f / fmaxf((float)(p1 - p0), 1.0f);
  bufA[wv*68 + l] = acc * invr;
  if (l < 4) {
    float mean = sc / fmaxf(cnt, 1.0f);
    bufA[wv*68 + 64 + l] = mean;
    if (l == 0) jsf2[s2*20 + 18] = mean;
    if (l == 1) jsf2[s2*20 + 19] = mean;
  }
  __syncthreads();
  block_layer<68,100,4,true>(t2_wi, t2_bi, bufA, bufB, tid);
  block_layer<100,100,4,true>(t2_wh, t2_bh, bufB, bufA, tid);
  block_layer<100,100,4,true>(t2_wh+10000, t2_bh+100, bufA, bufB, tid);
  block_layer<100,64,4,false>(t2_wo, t2_bo, bufB, bufA, tid);
  int r0 = blockIdx.x*4;
  for (int o2 = tid; o2 < 4*64; o2 += 256) x2fc[r0*64 + o2] = bufA[o2];
}

// ==================== K4: gc2 + q-MLP(x2) (4 rows/block, 128 blocks) ====================
__global__ __launch_bounds__(256) void k4_gc2_q(
    const int* __restrict__ startE, const int* __restrict__ elist,
    const float* __restrict__ xin,
    const float* wn, const float* wsf, const float* bias,
    const float* q_wi, const float* q_bi, const float* q_wh, const float* q_bh,
    const float* q_wo, const float* q_bo,
    float* __restrict__ out_f, float* __restrict__ jsf2) {
  int tid = threadIdx.x, wv = tid >> 6, l = tid & 63;
  int d = blockIdx.x*4 + wv;
  __shared__ __align__(16) float bufA[4*100];
  __shared__ __align__(16) float bufB[4*100];
  __shared__ float smW[4*128];
  float* sm = smW + wv*128;
  sm[l]      = edge_mean(elist, xin, startE[d], startE[d+1], l);
  sm[64 + l] = xin[d*64 + l];
  __syncthreads();
  float o = bias[l];
  #pragma unroll 8
  for (int k = 0; k < 64; ++k)
    o += sm[k]*wn[k*64 + l] + sm[64 + k]*wsf[k*64 + l];
  out_f[d*64 + l] = o;
  bufA[wv*64 + l] = o;
  __syncthreads();
  block_layer<64,100,4,true>(q_wi, q_bi, bufA, bufB, tid);
  block_layer<100,100,4,true>(q_wh, q_bh, bufB, bufA, tid);
  block_layer<100,100,4,true>(q_wh+10000, q_bh+100, bufA, bufB, tid);
  block_layer<100,18,4,false>(q_wo, q_bo, bufB, bufA, tid);
  int r0 = blockIdx.x*4;
  for (int o2 = tid; o2 < 4*18; o2 += 256) {
    int r = o2 / 18, c = o2 - r*18;
    jsf2[(r0+r)*20 + c] = bufA[o2];
  }
}

// ---------------- quadratic render (float4 jsf reads) ----------------
__global__ __launch_bounds__(256) void render_kernel(
    const int* __restrict__ cluster1, const int* __restrict__ cluster2,
    const float* __restrict__ jsf1, const float* __restrict__ jsf2,
    float* __restrict__ r1, float* __restrict__ r2) {
  int n = blockIdx.x*256 + threadIdx.x;
  int p = n & 65535, i = p >> 8, j = p & 255;
  float gy = i * (1.0f/256.0f), gx = j * (1.0f/256.0f);
  int s = cluster1[n];
  {
    const float4* f4 = reinterpret_cast<const float4*>(jsf1 + s*20);
    float4 v0 = f4[0], v1 = f4[1], v2 = f4[2], v3 = f4[3], v4 = f4[4];
    float dx = gy - v0.x, dy = gx - v0.y;
    float dxx = dx*dx, dyy = dy*dy, dxy = dx*dy;
    r1[n*3 + 0] = v0.z + v0.w*dx + v1.x*dy + v1.y*dxx + v1.z*dyy + v1.w*dxy;
    r1[n*3 + 1] = v2.x + v2.y*dx + v2.z*dy + v2.w*dxx + v3.x*dyy + v3.y*dxy;
    r1[n*3 + 2] = v3.z + v3.w*dx + v4.x*dy + v4.y*dxx + v4.z*dyy + v4.w*dxy;
  }
  int s2 = cluster2[s];
  {
    const float4* f4 = reinterpret_cast<const float4*>(jsf2 + s2*20);
    float4 v0 = f4[0], v1 = f4[1], v2 = f4[2], v3 = f4[3], v4 = f4[4];
    float dx = gy - v0.x, dy = gx - v0.y;
    float dxx = dx*dx, dyy = dy*dy, dxy = dx*dy;
    r2[n*3 + 0] = v0.z + v0.w*dx + v1.x*dy + v1.y*dxx + v1.z*dyy + v1.w*dxy;
    r2[n*3 + 1] = v2.x + v2.y*dx + v2.z*dy + v2.w*dxx + v3.x*dyy + v3.y*dxy;
    r2[n*3 + 2] = v3.z + v3.w*dx + v4.x*dy + v4.y*dxx + v4.z*dyy + v4.w*dxy;
  }
}

extern "C" void kernel_launch(void* const* d_in, const int* in_sizes, int n_in,
                              void* d_out, int out_size, void* d_ws, size_t ws_size,
                              hipStream_t stream) {
  const float* img    = (const float*)d_in[0];
  const float* conv_w = (const float*)d_in[1];
  const float* conv_b = (const float*)d_in[2];
  const float* t1_wi = (const float*)d_in[3];  const float* t1_bi = (const float*)d_in[4];
  const float* t1_wh = (const float*)d_in[5];  const float* t1_bh = (const float*)d_in[6];
  const float* t1_wo = (const float*)d_in[7];  const float* t1_bo = (const float*)d_in[8];
  const float* t2_wi = (const float*)d_in[9];  const float* t2_bi = (const float*)d_in[10];
  const float* t2_wh = (const float*)d_in[11]; const float* t2_bh = (const float*)d_in[12];
  const float* t2_wo = (const float*)d_in[13]; const float* t2_bo = (const float*)d_in[14];
  const float* q_wi  = (const float*)d_in[15]; const float* q_bi  = (const float*)d_in[16];
  const float* q_wh  = (const float*)d_in[17]; const float* q_bh  = (const float*)d_in[18];
  const float* q_wo  = (const float*)d_in[19]; const float* q_bo  = (const float*)d_in[20];
  const float* gc1_wn = (const float*)d_in[21]; const float* gc1_ws = (const float*)d_in[22];
  const float* gc1_b  = (const float*)d_in[23];
  const float* gc2_wn = (const float*)d_in[24]; const float* gc2_ws = (const float*)d_in[25];
  const float* gc2_b  = (const float*)d_in[26];
  const int* cluster1 = (const int*)d_in[27];
  const int* cluster2 = (const int*)d_in[28];
  const int* edges1   = (const int*)d_in[29];
  const int* edges2   = (const int*)d_in[30];

  float* ws = (float*)d_ws;
  int*   wsI = (int*)d_ws;
  float* out  = (float*)d_out;
  float* o_r1 = out;
  float* o_r2 = out + 786432;
  float* o_x1 = out + 1572864;
  float* o_x2 = out + 1835008;

  // prep: zero histograms + padded image (one launch)
  prep<<<(PAD_TOT + 255)/256, 256, 0, stream>>>(img, ws + OFF_PAD, wsI);

  constexpr int TOTW = NPIX + M1C + E1C + E2C;   // 339968, /256 = 1328 exact
  build_hist<<<TOTW/256, 256, 0, stream>>>(cluster1, cluster2, edges1, edges2, wsI);
  scan_kernel<<<4, 1024, 0, stream>>>(wsI);
  scatter_all<<<TOTW/256, 256, 0, stream>>>(cluster1, cluster2, edges1, edges2, wsI);

  // K1: padded-img gather + t1 MLP (8 clusters/block, 512 blocks)
  k1_gather_t1<<<M1C/8, 256, 0, stream>>>(ws + OFF_PAD, conv_w, conv_b,
      wsI+IOFF_ST1, wsI+IOFF_PLIST,
      t1_wi, t1_bi, t1_wh, t1_bh, t1_wo, t1_bo,
      ws+OFF_X1FC, ws+OFF_S1CR, ws+OFF_C1, ws+OFF_JSF1);

  // K2: graph conv 1 + q MLP on x1 rows (8 dst/block, 512 blocks)
  k2_gc1_q<<<M1C/8, 256, 0, stream>>>(wsI+IOFF_STE1, wsI+IOFF_E1L, ws+OFF_X1FC,
      gc1_wn, gc1_ws, gc1_b,
      q_wi, q_bi, q_wh, q_bh, q_wo, q_bo,
      ws+OFF_X1, o_x1, ws+OFF_JSF1);

  // K3: level-2 pooling + t2 MLP
  k3_pool_t2<<<M2C/4, 256, 0, stream>>>(wsI+IOFF_STC2, wsI+IOFF_R2L,
      ws+OFF_X1, ws+OFF_S1CR, ws+OFF_C1,
      t2_wi, t2_bi, t2_wh, t2_bh, t2_wo, t2_bo,
      ws+OFF_X2FC, ws+OFF_JSF2);

  // K4: graph conv 2 + q MLP on x2 rows
  k4_gc2_q<<<M2C/4, 256, 0, stream>>>(wsI+IOFF_STE2, wsI+IOFF_E2L, ws+OFF_X2FC,
      gc2_wn, gc2_ws, gc2_b,
      q_wi, q_bi, q_wh, q_bh, q_wo, q_bo,
      o_x2, ws+OFF_JSF2);

  // render
  render_kernel<<<NPIX/256, 256, 0, stream>>>(cluster1, cluster2, ws+OFF_JSF1, ws+OFF_JSF2, o_r1, o_r2);
}